// Round 8
// baseline (776.993 us; speedup 1.0000x reference)
//
#include <hip/hip_runtime.h>
#include <hip/hip_fp16.h>
#include <hip/hip_fp8.h>
#include <cstdint>

#define B_   4
#define S_   19
#define HW_  16384
#define P_   65536
#define C_   256
#define Q_   256
#define NEG_ 512
#define NS_  131072
#define GENV_ 144
#define NANCH (S_ * 256)     // 4864
#define NPAIR (NANCH / 2)    // 2432
#define NBUCK 8

typedef float v2f __attribute__((ext_vector_type(2)));

#if __has_builtin(__builtin_amdgcn_cvt_pk_f32_fp8) && __has_builtin(__builtin_amdgcn_cvt_pk_fp8_f32)
#define HAVE_HW_FP8 1
#endif

template<int W> __device__ __forceinline__ v2f cvt8(uint32_t d) {
#ifdef HAVE_HW_FP8
  v2f r = __builtin_amdgcn_cvt_pk_f32_fp8((int)d, W);
  return r;
#else
  __hip_fp8_e4m3 h0, h1;
  h0.__x = (uint8_t)(d >> (W * 16));
  h1.__x = (uint8_t)(d >> (W * 16 + 8));
  v2f r; r.x = (float)h0; r.y = (float)h1; return r;
#endif
}
template<int W> __device__ __forceinline__ uint32_t pk8(float a, float b, uint32_t old) {
#ifdef HAVE_HW_FP8
  return (uint32_t)__builtin_amdgcn_cvt_pk_fp8_f32(a, b, (int)old, W);
#else
  __hip_fp8_e4m3 ha(a), hb(b);
  uint32_t v = (uint32_t)ha.__x | ((uint32_t)hb.__x << 8);
  return (old & (W ? 0x0000FFFFu : 0xFFFF0000u)) | (v << (W * 16));
#endif
}

// ---------------- threefry2x32 (JAX-exact) ----------------
__device__ __forceinline__ void tf2x32(uint32_t k0, uint32_t k1, uint32_t x0, uint32_t x1,
                                       uint32_t& o0, uint32_t& o1) {
  uint32_t k2 = k0 ^ k1 ^ 0x1BD11BDAu;
#define TFR(r) { x0 += x1; x1 = (x1 << r) | (x1 >> (32 - r)); x1 ^= x0; }
  x0 += k0; x1 += k1;
  TFR(13) TFR(15) TFR(26) TFR(6)  x0 += k1; x1 += k2 + 1u;
  TFR(17) TFR(29) TFR(16) TFR(24) x0 += k2; x1 += k0 + 2u;
  TFR(13) TFR(15) TFR(26) TFR(6)  x0 += k0; x1 += k1 + 3u;
  TFR(17) TFR(29) TFR(16) TFR(24) x0 += k1; x1 += k2 + 4u;
  TFR(13) TFR(15) TFR(26) TFR(6)  x0 += k2; x1 += k0 + 5u;
#undef TFR
  o0 = x0; o1 = x1;
}

__device__ __forceinline__ uint32_t rbits(uint32_t k0, uint32_t k1, uint32_t n) {
  uint32_t a, b; tf2x32(k0, k1, 0u, n, a, b); return a ^ b;
}

__device__ __forceinline__ float bits2f01(uint32_t b) {
  return __uint_as_float((b >> 9) | 0x3f800000u) - 1.0f;
}

__device__ __forceinline__ float fastrcp(float x) {
  float r; asm("v_rcp_f32 %0, %1" : "=v"(r) : "v"(x)); return r;
}

__device__ __forceinline__ float wred(float v) {
#pragma unroll
  for (int off = 32; off > 0; off >>= 1) v += __shfl_xor(v, off, 64);
  return v;
}
__device__ __forceinline__ void wred3(float& a, float& b, float& c) {
#pragma unroll
  for (int off = 32; off > 0; off >>= 1) {
    a += __shfl_xor(a, off, 64);
    b += __shfl_xor(b, off, 64);
    c += __shfl_xor(c, off, 64);
  }
}

__device__ __forceinline__ void lse_up(float lg, float& m, float& l) {
  if (lg > m) { l = l * __expf(m - lg) + 1.0f; m = lg; }
  else l += __expf(lg - m);
}
__device__ __forceinline__ void lse_merge(float& m, float& l, float mo, float lo) {
  float mn = fmaxf(m, mo);
  l = l * __expf(m - mn) + lo * __expf(mo - mn);
  m = mn;
}

// XLA ErfInv32 (Giles)
__device__ __forceinline__ float erfinv_f(float x) {
  float w = -__logf(fmaxf(fmaf(-x, x, 1.0f), 1e-37f));
  float p;
  if (w < 5.0f) {
    w -= 2.5f;
    p = 2.81022636e-08f;
    p = fmaf(p, w, 3.43273939e-07f);
    p = fmaf(p, w, -3.5233877e-06f);
    p = fmaf(p, w, -4.39150654e-06f);
    p = fmaf(p, w, 0.00021858087f);
    p = fmaf(p, w, -0.00125372503f);
    p = fmaf(p, w, -0.00417768164f);
    p = fmaf(p, w, 0.246640727f);
    p = fmaf(p, w, 1.50140941f);
  } else {
    w = sqrtf(w) - 3.0f;
    p = -0.000200214257f;
    p = fmaf(p, w, 0.000100950558f);
    p = fmaf(p, w, 0.00134934322f);
    p = fmaf(p, w, -0.00367342844f);
    p = fmaf(p, w, 0.00573950773f);
    p = fmaf(p, w, -0.0076224613f);
    p = fmaf(p, w, 0.00943887047f);
    p = fmaf(p, w, 1.00167406f);
    p = fmaf(p, w, 2.83297682f);
  }
  return p * x;
}

// ---------------- K0: per-class keys ----------------
__global__ void k_keys(uint32_t* __restrict__ keys) {
  int i = threadIdx.x;
  if (i >= S_) return;
  uint32_t f0, f1;
  tf2x32(0u, 1234u, 0u, (uint32_t)i, f0, f1);
#pragma unroll
  for (int t = 0; t < 4; ++t) {
    uint32_t a, b;
    tf2x32(f0, f1, 0u, (uint32_t)t, a, b);
    keys[i * 8 + t * 2] = a; keys[i * 8 + t * 2 + 1] = b;
  }
}

// ---------------- K1: class id + hard flag ----------------
__global__ __launch_bounds__(256) void k_classify(const float* __restrict__ label,
    const float* __restrict__ mask, const float* __restrict__ prob,
    int* __restrict__ cls, int* __restrict__ hrd) {
  int p = blockIdx.x * 256 + threadIdx.x;
  int b = p >> 14, rem = p & (HW_ - 1);
  int sp = -1;
#pragma unroll
  for (int s = 0; s < S_; ++s) {
    float l = label[((b * S_ + s) << 14) + rem];
    if (l > 0.5f) sp = s;
  }
  if (mask[(b << 14) + rem] <= 0.5f) sp = -1;
  int h = 0;
  if (sp >= 0) h = (prob[((b * S_ + sp) << 14) + rem] < 0.97f) ? 1 : 0;
  cls[p] = sp; hrd[p] = h;
}

// ---------------- K1b: pack (B,C,H,W) f32 -> (P) rows of [64 mu dwords | 64 sg dwords] fp8 ----------------
__global__ __launch_bounds__(256) void k_pack(const float* __restrict__ mu,
    const float* __restrict__ sg, uint32_t* __restrict__ pair8, float* __restrict__ norm2) {
  __shared__ float smu[64][65];
  __shared__ float ssg[64][65];
  int p0 = blockIdx.x * 64, c0 = blockIdx.y * 64;
  int b = p0 >> 14, rem0 = p0 & (HW_ - 1);
  int cl0 = threadIdx.x >> 4, px4 = (threadIdx.x & 15) * 4;
#pragma unroll
  for (int itr = 0; itr < 4; ++itr) {
    int cl = cl0 + itr * 16;
    int addr = ((b * C_ + c0 + cl) << 14) + rem0 + px4;
    float4 vm = *reinterpret_cast<const float4*>(mu + addr);
    float4 vs = *reinterpret_cast<const float4*>(sg + addr);
    smu[cl][px4 + 0] = vm.x; smu[cl][px4 + 1] = vm.y;
    smu[cl][px4 + 2] = vm.z; smu[cl][px4 + 3] = vm.w;
    ssg[cl][px4 + 0] = vs.x; ssg[cl][px4 + 1] = vs.y;
    ssg[cl][px4 + 2] = vs.z; ssg[cl][px4 + 3] = vs.w;
  }
  __syncthreads();
#pragma unroll
  for (int itr = 0; itr < 4; ++itr) {
    int e = itr * 256 + threadIdx.x;
    int pxl = e >> 4, dq = e & 15;
    int cb = dq * 4;
    uint32_t wm = pk8<0>(smu[cb][pxl], smu[cb + 1][pxl], 0u);
    wm = pk8<1>(smu[cb + 2][pxl], smu[cb + 3][pxl], wm);
    uint32_t wsv = pk8<0>(ssg[cb][pxl], ssg[cb + 1][pxl], 0u);
    wsv = pk8<1>(ssg[cb + 2][pxl], ssg[cb + 3][pxl], wsv);
    size_t rowb = (size_t)(p0 + pxl) * 128;
    pair8[rowb + (c0 >> 2) + dq] = wm;
    pair8[rowb + 64 + (c0 >> 2) + dq] = wsv;
  }
  int pxn = threadIdx.x >> 2, qn = threadIdx.x & 3;
  float s2 = 0.f;
#pragma unroll
  for (int k = 0; k < 16; ++k) { float v = smu[qn * 16 + k][pxn]; s2 = fmaf(v, v, s2); }
  s2 += __shfl_xor(s2, 1, 64);
  s2 += __shfl_xor(s2, 2, 64);
  if (qn == 0) atomicAdd(&norm2[p0 + pxn], s2);
}

// ---------------- K2: ordered per-class pixel lists ----------------
__global__ __launch_bounds__(256) void k_count(const int* __restrict__ cls, const int* __restrict__ hrd,
    int* __restrict__ bcv, int* __restrict__ bch) {
  __shared__ int hv[S_], hh[S_];
  int t = threadIdx.x;
  if (t < S_) { hv[t] = 0; hh[t] = 0; }
  __syncthreads();
  int p = blockIdx.x * 256 + t;
  int s = cls[p];
  if (s >= 0) { atomicAdd(&hv[s], 1); if (hrd[p]) atomicAdd(&hh[s], 1); }
  __syncthreads();
  if (t < S_) { bcv[t * 256 + blockIdx.x] = hv[t]; bch[t * 256 + blockIdx.x] = hh[t]; }
}

// parallel two-level scan: 304 workers of 16-entry chunks
__global__ __launch_bounds__(320) void k_scan(const int* __restrict__ bcv, const int* __restrict__ bch,
    int* __restrict__ bov, int* __restrict__ boh,
    int* __restrict__ cntv, int* __restrict__ cnth,
    int* __restrict__ basev, int* __restrict__ baseh) {
  __shared__ int psv[S_][16], psh[S_][16], scv[S_], sch[S_];
  int t = threadIdx.x;
  int s = t >> 4, c = t & 15;
  if (t < 304) {
    int sv = 0, sh = 0;
#pragma unroll 4
    for (int b = 0; b < 16; ++b) {
      sv += bcv[s * 256 + c * 16 + b];
      sh += bch[s * 256 + c * 16 + b];
    }
    psv[s][c] = sv; psh[s][c] = sh;
  }
  __syncthreads();
  if (t < S_) {
    int rv = 0, rh = 0;
#pragma unroll
    for (int cc = 0; cc < 16; ++cc) {
      int tv = psv[t][cc]; psv[t][cc] = rv; rv += tv;
      int th = psh[t][cc]; psh[t][cc] = rh; rh += th;
    }
    cntv[t] = rv; cnth[t] = rh; scv[t] = rv; sch[t] = rh;
  }
  __syncthreads();
  if (t == 0) {
    int bv = 0, bh = 0;
    for (int k = 0; k < S_; ++k) { basev[k] = bv; bv += scv[k]; baseh[k] = bh; bh += sch[k]; }
  }
  if (t < 304) {
    int rv = psv[s][c], rh = psh[s][c];
#pragma unroll 4
    for (int b = 0; b < 16; ++b) {
      int i0 = s * 256 + c * 16 + b;
      int tv = bcv[i0]; bov[i0] = rv; rv += tv;
      int th = bch[i0]; boh[i0] = rh; rh += th;
    }
  }
}

__global__ __launch_bounds__(256) void k_fill(const int* __restrict__ cls, const int* __restrict__ hrd,
    const int* __restrict__ bov, const int* __restrict__ boh,
    const int* __restrict__ basev, const int* __restrict__ baseh,
    int* __restrict__ posv, int* __restrict__ posh) {
  __shared__ int lc[256], lh[256];
  int t = threadIdx.x;
  int p = blockIdx.x * 256 + t;
  int s = cls[p]; int h = hrd[p];
  lc[t] = s; lh[t] = h;
  __syncthreads();
  if (s >= 0) {
    int rv = 0, rh = 0;
    for (int k = 0; k < t; ++k) { if (lc[k] == s) { rv++; rh += lh[k]; } }
    posv[basev[s] + bov[s * 256 + blockIdx.x] + rv] = p;
    if (h) posh[baseh[s] + boh[s * 256 + blockIdx.x] + rh] = p;
  }
}

// ---------------- K3: per-class partial sums (plane layout) ----------------
__global__ __launch_bounds__(256) void k_sums(const uint32_t* __restrict__ pair8,
    const int* __restrict__ cls, float* __restrict__ part) {
  __shared__ float lacc[S_][2][C_];
  __shared__ int scls[256];
  int t = threadIdx.x;
  for (int e = t; e < S_ * 2 * C_; e += 256) (&lacc[0][0][0])[e] = 0.f;
  int p0 = blockIdx.x * 256;
  scls[t] = cls[p0 + t];
  __syncthreads();
  int dq = t >> 2, sub = t & 3;
  for (int pp = 0; pp < 256; ++pp) {
    int s = scls[pp];
    size_t rowb = (size_t)(p0 + pp) * 128;
    uint32_t dm = pair8[rowb + dq];
    uint32_t dsv = pair8[rowb + 64 + dq];
    if (s >= 0) {
      v2f em = (sub & 2) ? cvt8<1>(dm) : cvt8<0>(dm);
      v2f es = (sub & 2) ? cvt8<1>(dsv) : cvt8<0>(dsv);
      float mv = (sub & 1) ? em.y : em.x;
      float sv = (sub & 1) ? es.y : es.x;
      float ia = fastrcp(sv);
      lacc[s][0][t] += ia;
      lacc[s][1][t] += ia * mv;
    }
  }
  __syncthreads();
  float* dst = part + (size_t)blockIdx.x * (2 * S_ * C_);
  for (int e = t; e < S_ * 2 * C_; e += 256) dst[e] = (&lacc[0][0][0])[e];
}

// ---------------- K4: prototypes (reduce partials here) ----------------
__global__ __launch_bounds__(256) void k_proto(const float* __restrict__ part,
    const float* __restrict__ mmu, const float* __restrict__ msg,
    float* __restrict__ pmu, float* __restrict__ psig, float* __restrict__ phat) {
  int s = blockIdx.x, c = threadIdx.x;
  float A = 0.f, Bv = 0.f;
  for (int b = 0; b < 256; ++b) {
    const float* pb = part + (size_t)b * (2 * S_ * C_) + (s * 2) * C_;
    A += pb[c];
    Bv += pb[C_ + c];
  }
  int e = s * C_ + c;
  float psb = 1.0f / A;
  float pmb = psb * Bv;
  float ms = msg[e], mm = mmu[e];
  float ps = 1.0f / (1.0f / psb + 1.0f / ms);
  float pm = ps * (mm / ms + pmb / psb);
  pmu[e] = pm; psig[e] = ps;
  __shared__ float red[4];
  float w = wred(pm * pm);
  int lane = c & 63, wv = c >> 6;
  if (lane == 0) red[wv] = w;
  __syncthreads();
  float tot = red[0] + red[1] + red[2] + red[3];
  float nrm = fmaxf(sqrtf(tot), 1e-12f);
  phat[e] = pm / nrm;
}

// ---------------- K5a: sim -> log_softmax ----------------
__global__ __launch_bounds__(64) void k_simlogp(const float* __restrict__ phat,
    const float* __restrict__ psig, float* __restrict__ logp) {
  int i = blockIdx.x, lane = threadIdx.x;
  int c0 = lane * 4;
  float phi[4], psi[4];
#pragma unroll
  for (int k = 0; k < 4; ++k) { phi[k] = phat[i * C_ + c0 + k]; psi[k] = psig[i * C_ + c0 + k]; }
  float xs[18];
#pragma unroll
  for (int j = 0; j < 18; ++j) {
    int o = i + 1 + j; if (o >= S_) o -= S_;
    float t = 0.f;
#pragma unroll
    for (int k = 0; k < 4; ++k) {
      float d = phi[k] - phat[o * C_ + c0 + k];
      float dn = psi[k] + psig[o * C_ + c0 + k];
      t += d * d / dn + logf(dn);
    }
    t = wred(t);
    xs[j] = (-0.5f * t * (1.0f / 256.0f)) * 2.0f;
  }
  float m = xs[0];
#pragma unroll
  for (int j = 1; j < 18; ++j) m = fmaxf(m, xs[j]);
  float se = 0.f;
#pragma unroll
  for (int j = 0; j < 18; ++j) se += expf(xs[j] - m);
  float lg = logf(se);
  if (lane == 0) {
#pragma unroll
    for (int j = 0; j < 18; ++j) logp[i * 18 + j] = xs[j] - m - lg;
  }
}

// ---------------- K5d: anchors ----------------
__global__ __launch_bounds__(256) void k_anchors(const uint32_t* __restrict__ keys,
    const int* __restrict__ cnth, const int* __restrict__ baseh,
    const int* __restrict__ posh, int* __restrict__ aidx) {
  int i = blockIdx.x, q = threadIdx.x;
  uint32_t k0 = keys[i * 8 + 0], k1 = keys[i * 8 + 1];
  float u = bits2f01(rbits(k0, k1, (uint32_t)q));
  int cnt = cnth[i];
  int idx = P_ - 1;
  if (cnt > 0) {
    int kk = (int)(u * (float)cnt);
    if (kk >= cnt) kk = cnt - 1;
    idx = posh[baseh[i] + kk];
  }
  aidx[i * Q_ + q] = idx;
}

// ---------------- K5c: generalized prototypes ----------------
__global__ __launch_bounds__(256) void k_gen(const uint32_t* __restrict__ keys,
    const float* __restrict__ pmu, const float* __restrict__ psig, float* __restrict__ ghat) {
  int v = blockIdx.x, i = blockIdx.y, c = threadIdx.x;
  int o = i + 1 + (v >> 3); if (o >= S_) o -= S_;
  uint32_t k0 = keys[i * 8 + 6], k1 = keys[i * 8 + 7];
  uint32_t bits = rbits(k0, k1, (uint32_t)(v * C_ + c));
  float f01 = bits2f01(bits);
  const float lo = -0.99999994f;
  float u = fmaxf(f01 * 2.0f + lo, lo);
  float eps = 1.41421356237f * erfinv_f(u);
  float g = pmu[o * C_ + c] + sqrtf(psig[o * C_ + c]) * eps;
  __shared__ float red[4];
  float w = wred(g * g);
  int lane = c & 63, wv = c >> 6;
  if (lane == 0) red[wv] = w;
  __syncthreads();
  float tot = red[0] + red[1] + red[2] + red[3];
  float nrm = fmaxf(sqrtf(tot), 1e-12f);
  ghat[((size_t)(i * GENV_ + v)) * C_ + c] = g / nrm;
}

// ---------------- K5b: class + negative sampling ----------------
__global__ __launch_bounds__(256) void k_sample(const uint32_t* __restrict__ keys,
    const float* __restrict__ logp, const int* __restrict__ cntv, const int* __restrict__ basev,
    const int* __restrict__ posv, int* __restrict__ nidx) {
  int i = blockIdx.y;
  int m = blockIdx.x * 256 + threadIdx.x;
  __shared__ float lp[18];
  __shared__ int lcnt[S_], lbase[S_];
  int t = threadIdx.x;
  if (t < 18) lp[t] = logp[i * 18 + t];
  if (t < S_) { lcnt[t] = cntv[t]; lbase[t] = basev[t]; }
  __syncthreads();
  uint32_t kc0 = keys[i * 8 + 2], kc1 = keys[i * 8 + 3];
  uint32_t kn0 = keys[i * 8 + 4], kn1 = keys[i * 8 + 5];
  float bv = -1e30f; int best = 0;
  for (int s = 0; s < 18; ++s) {
    uint32_t b = rbits(kc0, kc1, (uint32_t)m * 18u + (uint32_t)s);
    float u = fmaxf(bits2f01(b), 1.17549435e-38f);
    float g = -__logf(-__logf(u)) + lp[s];
    if (g > bv) { bv = g; best = s; }
  }
  float un = bits2f01(rbits(kn0, kn1, (uint32_t)m));
  int cc = i + 1 + best; if (cc >= S_) cc -= S_;
  int cnt = lcnt[cc];
  int idx = P_ - 1;
  if (cnt > 0) {
    int kk = (int)(un * (float)cnt);
    if (kk >= cnt) kk = cnt - 1;
    idx = posv[lbase[cc] + kk];
  }
  nidx[(size_t)i * NS_ + m] = idx;
}

// ---------------- K5e: per-anchor bucket sort of negatives (deterministic) ----------------
__global__ __launch_bounds__(64) void k_bucket(const int* __restrict__ nidx,
    int* __restrict__ snidx, int* __restrict__ boff) {
  int a = blockIdx.x;
  int lane = threadIdx.x;
  const int* src = nidx + (size_t)a * NEG_;
  int e[8], bk[8];
#pragma unroll
  for (int c = 0; c < 8; ++c) { e[c] = src[c * 64 + lane]; bk[c] = (e[c] >> 13) & 7; }
  uint32_t cnt[NBUCK];
#pragma unroll
  for (int b = 0; b < NBUCK; ++b) cnt[b] = 0;
#pragma unroll
  for (int c = 0; c < 8; ++c)
#pragma unroll
    for (int b = 0; b < NBUCK; ++b) {
      unsigned long long mb = __ballot(bk[c] == b);
      cnt[b] += (uint32_t)__popcll(mb);
    }
  uint32_t base[NBUCK]; uint32_t run = 0;
#pragma unroll
  for (int b = 0; b < NBUCK; ++b) { base[b] = run; run += cnt[b]; }
  if (lane < NBUCK) boff[a * 9 + lane] = (int)base[lane];
  if (lane == 0) boff[a * 9 + 8] = NEG_;
  uint32_t off[NBUCK];
#pragma unroll
  for (int b = 0; b < NBUCK; ++b) off[b] = 0;
  unsigned long long ltm = (1ull << lane) - 1ull;
#pragma unroll
  for (int c = 0; c < 8; ++c) {
    int pos = 0;
#pragma unroll
    for (int b = 0; b < NBUCK; ++b) {
      unsigned long long mb = __ballot(bk[c] == b);
      if (bk[c] == b) pos = (int)(base[b] + off[b] + (uint32_t)__popcll(mb & ltm));
      off[b] += (uint32_t)__popcll(mb);
    }
    snidx[(size_t)a * NEG_ + pos] = e[c];
  }
}

// ---------------- K6a: negatives — plane layout + packed-f32 inner loop ----------------
#define PKQ(DM, DS, QI) {                                         \
    float4 ah4 = AH[QI]; float4 as4 = AS[QI]; float4 h24 = H2[QI];\
    v2f m01 = cvt8<0>(DM), m23 = cvt8<1>(DM);                     \
    v2f g01 = cvt8<0>(DS), g23 = cvt8<1>(DS);                     \
    v2f asA; asA.x = as4.x; asA.y = as4.y;                        \
    v2f asB; asB.x = as4.z; asB.y = as4.w;                        \
    v2f dA = asA + g01;                                           \
    v2f dB = asB + g23;                                           \
    float dpA = dA.x * dA.y, dpB = dB.x * dB.y;                   \
    float RA = fastrcp(dpA), RB = fastrcp(dpB);                   \
    pp *= dpA * dpB;                                              \
    v2f rA; rA.x = dA.y * RA; rA.y = dA.x * RA;                   \
    v2f rB; rB.x = dB.y * RB; rB.y = dB.x * RB;                   \
    v2f h2A; h2A.x = h24.x; h2A.y = h24.y;                        \
    v2f h2B; h2B.x = h24.z; h2B.y = h24.w;                        \
    sAv += h2A * rA; sAv += h2B * rB;                             \
    v2f qA = m01 * rA, qB = m23 * rB;                             \
    v2f ahA; ahA.x = ah4.x; ahA.y = ah4.y;                        \
    v2f ahB; ahB.x = ah4.z; ahB.y = ah4.w;                        \
    sCv += ahA * qA; sCv += ahB * qB;                             \
    sNRv += m01 * qA; sNRv += m23 * qB; }

__global__ __launch_bounds__(64) void k_neg(const uint32_t* __restrict__ pair8,
    const float* __restrict__ norm2, const int* __restrict__ snidx,
    const int* __restrict__ boff, const int* __restrict__ aidx,
    float2* __restrict__ partial) {
  __shared__ float4 ahP[2][66];
  __shared__ float4 asP[2][66];
  __shared__ float4 h2P[2][66];
  int bid = blockIdx.x;
  int bucket = bid & 7;          // XCD-affine
  int pr = bid >> 3;
  int a0 = pr * 2, a1 = a0 + 1;
  int lane = threadIdx.x;

  int ap0 = aidx[a0], ap1 = aidx[a1];
  float rn0 = fastrcp(fmaxf(sqrtf(norm2[ap0]), 1e-12f));
  float rn1 = fastrcp(fmaxf(sqrtf(norm2[ap1]), 1e-12f));
  {
    const uint32_t* r0 = pair8 + (size_t)ap0 * 128;
    uint32_t dm = r0[lane], dsv = r0[64 + lane];
    v2f m01 = cvt8<0>(dm), m23 = cvt8<1>(dm);
    v2f s01 = cvt8<0>(dsv), s23 = cvt8<1>(dsv);
    float h0 = m01.x * rn0, h1 = m01.y * rn0, h2 = m23.x * rn0, h3 = m23.y * rn0;
    ahP[0][lane] = make_float4(h0, h1, h2, h3);
    asP[0][lane] = make_float4(s01.x, s01.y, s23.x, s23.y);
    h2P[0][lane] = make_float4(h0 * h0, h1 * h1, h2 * h2, h3 * h3);
    const uint32_t* r1 = pair8 + (size_t)ap1 * 128;
    dm = r1[lane]; dsv = r1[64 + lane];
    m01 = cvt8<0>(dm); m23 = cvt8<1>(dm);
    s01 = cvt8<0>(dsv); s23 = cvt8<1>(dsv);
    h0 = m01.x * rn1; h1 = m01.y * rn1; h2 = m23.x * rn1; h3 = m23.y * rn1;
    ahP[1][lane] = make_float4(h0, h1, h2, h3);
    asP[1][lane] = make_float4(s01.x, s01.y, s23.x, s23.y);
    h2P[1][lane] = make_float4(h0 * h0, h1 * h1, h2 * h2, h3 * h3);
  }
  __syncthreads();

  int s0 = boff[a0 * 9 + bucket], e0i = boff[a0 * 9 + bucket + 1];
  int s1 = boff[a1 * 9 + bucket], e1i = boff[a1 * 9 + bucket + 1];
  int L0 = e0i - s0, L1 = e1i - s1, Lt = L0 + L1;
  const int* list0 = snidx + (size_t)a0 * NEG_ + s0;
  const int* list1 = snidx + (size_t)a1 * NEG_ + s1;

  float m0 = -1e30f, l0 = 0.f, m1 = -1e30f, l1 = 0.f;

  for (int r = 0; r * 64 < Lt; ++r) {
    int g = r * 64 + lane;
    bool act = g < Lt;
    int which = (act && g >= L0) ? 1 : 0;
    int j = which ? (g - L0) : g;
    int p = act ? (which ? list1[j] : list0[j]) : ap0;
    float rnN = fastrcp(fmaxf(sqrtf(norm2[p]), 1e-12f));
    const uint4* rm = (const uint4*)(pair8 + (size_t)p * 128);   // mu plane: uint4 0..15
    const uint4* rs = rm + 16;                                   // sg plane: uint4 16..31
    const float4* AH = ahP[which];
    const float4* AS = asP[which];
    const float4* H2 = h2P[which];
    v2f sAv = {0.f, 0.f}, sCv = {0.f, 0.f}, sNRv = {0.f, 0.f};
    float sL = 0.f;
    uint4 cm = rm[0], cs = rs[0];
#pragma unroll 1
    for (int it = 0; it < 16; ++it) {
      int nx = (it + 1) & 15;
      uint4 nmv = rm[nx], nsv = rs[nx];
      float pp = 1.0f;
      PKQ(cm.x, cs.x, it * 4 + 0)
      PKQ(cm.y, cs.y, it * 4 + 1)
      PKQ(cm.z, cs.z, it * 4 + 2)
      PKQ(cm.w, cs.w, it * 4 + 3)
      sL += __logf(pp);          // 16-ch product, range [0.2^16, 2^16] — safe
      cm = nmv; cs = nsv;
    }
    float sA = sAv.x + sAv.y, sC = sCv.x + sCv.y, sNR = sNRv.x + sNRv.y;
    float tt = sA + rnN * rnN * sNR - 2.0f * rnN * sC + sL;
    float lg = -tt * (1.0f / 256.0f);
    if (act) { if (which) lse_up(lg, m1, l1); else lse_up(lg, m0, l0); }
  }
#pragma unroll
  for (int o = 32; o > 0; o >>= 1) {
    float mo = __shfl_xor(m0, o, 64), lo = __shfl_xor(l0, o, 64);
    lse_merge(m0, l0, mo, lo);
    mo = __shfl_xor(m1, o, 64); lo = __shfl_xor(l1, o, 64);
    lse_merge(m1, l1, mo, lo);
  }
  if (lane == 0) {
    partial[a0 * NBUCK + bucket] = make_float2(m0, l0);
    partial[a1 * NBUCK + bucket] = make_float2(m1, l1);
  }
}

// ---------------- K6b: pos + gens + merge partials ----------------
__global__ __launch_bounds__(256, 4) void k_fin(const uint32_t* __restrict__ pair8,
    const float* __restrict__ norm2,
    const float* __restrict__ phat, const float* __restrict__ psig,
    const float* __restrict__ ghat, const int* __restrict__ aidx,
    const float2* __restrict__ partial, float* __restrict__ out) {
  __shared__ float2 ancG[C_];   // {w, ahat*w}
  __shared__ float redm[3][4];
  __shared__ float2 mlw[4];

  int bid = blockIdx.x;
  int i = bid >> 8;
  int t = threadIdx.x, w = t >> 6, lane = t & 63;

  int ap = aidx[bid];
  uint32_t dm = pair8[(size_t)ap * 128 + (t >> 2)];
  uint32_t dsg = pair8[(size_t)ap * 128 + 64 + (t >> 2)];
  v2f em = (t & 2) ? cvt8<1>(dm) : cvt8<0>(dm);
  v2f es = (t & 2) ? cvt8<1>(dsg) : cvt8<0>(dsg);
  float amu = (t & 1) ? em.y : em.x;
  float asg = (t & 1) ? es.y : es.x;
  float rn = fastrcp(fmaxf(sqrtf(norm2[ap]), 1e-12f));
  float ahat = amu * rn;
  float wv = fastrcp(asg);
  ancG[t] = make_float2(wv, ahat * wv);

  float pm = phat[i * C_ + t];
  float ps = psig[i * C_ + t];
  float dnp = asg + ps;
  float dd = ahat - pm;
  float post = fmaf(dd * dd, fastrcp(dnp), __logf(dnp));
  float a1t = ahat * ahat * wv;
  float lat = __logf(asg);
  wred3(post, a1t, lat);
  if (lane == 0) { redm[0][w] = post; redm[1][w] = a1t; redm[2][w] = lat; }
  __syncthreads();
  float postS = redm[0][0] + redm[0][1] + redm[0][2] + redm[0][3];
  float Kc = (redm[1][0] + redm[1][1] + redm[1][2] + redm[1][3])
           + (redm[2][0] + redm[2][1] + redm[2][2] + redm[2][3]);
  float logit0 = -postS * (1.0f / 256.0f);

  float m = -1e30f, l = 0.0f;
  const float4* ancGf = (const float4*)ancG;
  if (lane < 36) {
    int g = lane * 4 + w;
    const float4* gp = (const float4*)(ghat + ((size_t)(i * GENV_ + g)) * C_);
    float a1 = 0.f, a2 = 0.f;
    for (int itr = 0; itr < 64; ++itr) {
      float4 gv = gp[itr];
      float4 g01 = ancGf[itr * 2];
      float4 g23 = ancGf[itr * 2 + 1];
      a1 = fmaf(gv.x * gv.x, g01.x, a1); a2 = fmaf(gv.x, g01.y, a2);
      a1 = fmaf(gv.y * gv.y, g01.z, a1); a2 = fmaf(gv.y, g01.w, a2);
      a1 = fmaf(gv.z * gv.z, g23.x, a1); a2 = fmaf(gv.z, g23.y, a2);
      a1 = fmaf(gv.w * gv.w, g23.z, a1); a2 = fmaf(gv.w, g23.w, a2);
    }
    float lg = -(Kc + a1 - 2.0f * a2) * (1.0f / 256.0f);
    lse_up(lg, m, l);
  }
#pragma unroll
  for (int o = 32; o > 0; o >>= 1) {
    float mo = __shfl_xor(m, o, 64);
    float lo = __shfl_xor(l, o, 64);
    lse_merge(m, l, mo, lo);
  }
  if (lane == 0) mlw[w] = make_float2(m, l);
  __syncthreads();
  if (t == 0) {
    float mm = mlw[0].x, ll = mlw[0].y;
    lse_merge(mm, ll, mlw[1].x, mlw[1].y);
    lse_merge(mm, ll, mlw[2].x, mlw[2].y);
    lse_merge(mm, ll, mlw[3].x, mlw[3].y);
    const float2* pp = partial + (size_t)bid * NBUCK;
#pragma unroll
    for (int b = 0; b < NBUCK; ++b) lse_merge(mm, ll, pp[b].x, pp[b].y);
    lse_merge(mm, ll, logit0, 1.0f);
    float lse = mm + __logf(ll);
    float contrib = logit0 - lse;
    atomicAdd(out, -contrib * (1.0f / (19.0f * 256.0f)));
  }
}

// ---------------- host ----------------
extern "C" void kernel_launch(void* const* d_in, const int* in_sizes, int n_in,
                              void* d_out, int out_size, void* d_ws, size_t ws_size,
                              hipStream_t stream) {
  const float* mu    = (const float*)d_in[0];
  const float* sg    = (const float*)d_in[1];
  const float* label = (const float*)d_in[2];
  const float* mask  = (const float*)d_in[3];
  const float* prob  = (const float*)d_in[4];
  const float* mmu   = (const float*)d_in[5];
  const float* msg   = (const float*)d_in[6];

  char* ws = (char*)d_ws;
  size_t off = 0;
  auto take = [&](size_t bytes) { size_t r = off; off = (off + bytes + 255) & ~(size_t)255; return r; };
  size_t o_pair8 = take((size_t)P_ * 128 * 4);   // 32 MB
  size_t o_norm2 = take((size_t)P_ * 4);
  size_t o_cls   = take((size_t)P_ * 4);
  size_t o_hrd   = take((size_t)P_ * 4);
  size_t o_bcv   = take(S_ * 256 * 4);
  size_t o_bch   = take(S_ * 256 * 4);
  size_t o_bov   = take(S_ * 256 * 4);
  size_t o_boh   = take(S_ * 256 * 4);
  size_t o_cntv  = take(S_ * 4);
  size_t o_cnth  = take(S_ * 4);
  size_t o_basev = take(S_ * 4);
  size_t o_baseh = take(S_ * 4);
  size_t o_posv  = take((size_t)P_ * 4);
  size_t o_posh  = take((size_t)P_ * 4);
  size_t o_part  = take((size_t)256 * 2 * S_ * C_ * 4);
  size_t o_pmu   = take(S_ * C_ * 4);
  size_t o_psig  = take(S_ * C_ * 4);
  size_t o_phat  = take(S_ * C_ * 4);
  size_t o_logp  = take(S_ * 18 * 4);
  size_t o_keys  = take(S_ * 8 * 4);
  size_t o_aidx  = take(S_ * Q_ * 4);
  size_t o_nidx  = take((size_t)S_ * NS_ * 4);
  size_t o_snidx = take((size_t)S_ * NS_ * 4);
  size_t o_boff  = take((size_t)NANCH * 9 * 4);
  size_t o_lpar  = take((size_t)NANCH * NBUCK * 8);
  size_t o_ghat  = take((size_t)S_ * GENV_ * C_ * 4);
  if (ws_size < off) return;

  uint32_t* pair8 = (uint32_t*)(ws + o_pair8);
  float*    norm2 = (float*)(ws + o_norm2);
  int*      cls   = (int*)(ws + o_cls);
  int*      hrd   = (int*)(ws + o_hrd);
  int*      bcv   = (int*)(ws + o_bcv);
  int*      bch   = (int*)(ws + o_bch);
  int*      bov   = (int*)(ws + o_bov);
  int*      boh   = (int*)(ws + o_boh);
  int*      cntv  = (int*)(ws + o_cntv);
  int*      cnth  = (int*)(ws + o_cnth);
  int*      basev = (int*)(ws + o_basev);
  int*      baseh = (int*)(ws + o_baseh);
  int*      posv  = (int*)(ws + o_posv);
  int*      posh  = (int*)(ws + o_posh);
  float*    part  = (float*)(ws + o_part);
  float*    pmu   = (float*)(ws + o_pmu);
  float*    psig  = (float*)(ws + o_psig);
  float*    phat  = (float*)(ws + o_phat);
  float*    logp  = (float*)(ws + o_logp);
  uint32_t* keys  = (uint32_t*)(ws + o_keys);
  int*      aidx  = (int*)(ws + o_aidx);
  int*      nidx  = (int*)(ws + o_nidx);
  int*      snidx = (int*)(ws + o_snidx);
  int*      boff  = (int*)(ws + o_boff);
  float2*   lpar  = (float2*)(ws + o_lpar);
  float*    ghat  = (float*)(ws + o_ghat);

  hipMemsetAsync(ws + o_norm2, 0, (size_t)P_ * 4, stream);
  hipMemsetAsync(d_out, 0, (size_t)out_size * 4, stream);

  k_keys<<<1, 64, 0, stream>>>(keys);
  k_classify<<<256, 256, 0, stream>>>(label, mask, prob, cls, hrd);
  k_pack<<<dim3(P_ / 64, C_ / 64), 256, 0, stream>>>(mu, sg, pair8, norm2);
  k_count<<<256, 256, 0, stream>>>(cls, hrd, bcv, bch);
  k_scan<<<1, 320, 0, stream>>>(bcv, bch, bov, boh, cntv, cnth, basev, baseh);
  k_fill<<<256, 256, 0, stream>>>(cls, hrd, bov, boh, basev, baseh, posv, posh);
  k_sums<<<256, 256, 0, stream>>>(pair8, cls, part);
  k_proto<<<S_, 256, 0, stream>>>(part, mmu, msg, pmu, psig, phat);
  k_simlogp<<<S_, 64, 0, stream>>>(phat, psig, logp);
  k_anchors<<<S_, 256, 0, stream>>>(keys, cnth, baseh, posh, aidx);
  k_gen<<<dim3(GENV_, S_), 256, 0, stream>>>(keys, pmu, psig, ghat);
  k_sample<<<dim3(512, S_), 256, 0, stream>>>(keys, logp, cntv, basev, posv, nidx);
  k_bucket<<<NANCH, 64, 0, stream>>>(nidx, snidx, boff);
  k_neg<<<NBUCK * NPAIR, 64, 0, stream>>>(pair8, norm2, snidx, boff, aidx, lpar);
  k_fin<<<NANCH, 256, 0, stream>>>(pair8, norm2, phat, psig, ghat, aidx, lpar, (float*)d_out);
}

// Round 9
// 616.162 us; speedup vs baseline: 1.2610x; 1.2610x over previous
//
#include <hip/hip_runtime.h>
#include <hip/hip_fp16.h>
#include <hip/hip_fp8.h>
#include <cstdint>

#define B_   4
#define S_   19
#define HW_  16384
#define P_   65536
#define C_   256
#define Q_   256
#define NEG_ 512
#define NS_  131072
#define GENV_ 144
#define NANCH (S_ * 256)     // 4864
#define NPAIR (NANCH / 2)    // 2432
#define NBUCK 8

typedef float v2f __attribute__((ext_vector_type(2)));

#if __has_builtin(__builtin_amdgcn_cvt_pk_f32_fp8) && __has_builtin(__builtin_amdgcn_cvt_pk_fp8_f32)
#define HAVE_HW_FP8 1
#endif

template<int W> __device__ __forceinline__ v2f cvt8(uint32_t d) {
#ifdef HAVE_HW_FP8
  v2f r = __builtin_amdgcn_cvt_pk_f32_fp8((int)d, W);
  return r;
#else
  __hip_fp8_e4m3 h0, h1;
  h0.__x = (uint8_t)(d >> (W * 16));
  h1.__x = (uint8_t)(d >> (W * 16 + 8));
  v2f r; r.x = (float)h0; r.y = (float)h1; return r;
#endif
}
template<int W> __device__ __forceinline__ uint32_t pk8(float a, float b, uint32_t old) {
#ifdef HAVE_HW_FP8
  return (uint32_t)__builtin_amdgcn_cvt_pk_fp8_f32(a, b, (int)old, W);
#else
  __hip_fp8_e4m3 ha(a), hb(b);
  uint32_t v = (uint32_t)ha.__x | ((uint32_t)hb.__x << 8);
  return (old & (W ? 0x0000FFFFu : 0xFFFF0000u)) | (v << (W * 16));
#endif
}

// ---------------- threefry2x32 (JAX-exact) ----------------
__device__ __forceinline__ void tf2x32(uint32_t k0, uint32_t k1, uint32_t x0, uint32_t x1,
                                       uint32_t& o0, uint32_t& o1) {
  uint32_t k2 = k0 ^ k1 ^ 0x1BD11BDAu;
#define TFR(r) { x0 += x1; x1 = (x1 << r) | (x1 >> (32 - r)); x1 ^= x0; }
  x0 += k0; x1 += k1;
  TFR(13) TFR(15) TFR(26) TFR(6)  x0 += k1; x1 += k2 + 1u;
  TFR(17) TFR(29) TFR(16) TFR(24) x0 += k2; x1 += k0 + 2u;
  TFR(13) TFR(15) TFR(26) TFR(6)  x0 += k0; x1 += k1 + 3u;
  TFR(17) TFR(29) TFR(16) TFR(24) x0 += k1; x1 += k2 + 4u;
  TFR(13) TFR(15) TFR(26) TFR(6)  x0 += k2; x1 += k0 + 5u;
#undef TFR
  o0 = x0; o1 = x1;
}

__device__ __forceinline__ uint32_t rbits(uint32_t k0, uint32_t k1, uint32_t n) {
  uint32_t a, b; tf2x32(k0, k1, 0u, n, a, b); return a ^ b;
}

__device__ __forceinline__ float bits2f01(uint32_t b) {
  return __uint_as_float((b >> 9) | 0x3f800000u) - 1.0f;
}

__device__ __forceinline__ float fastrcp(float x) {
  float r; asm("v_rcp_f32 %0, %1" : "=v"(r) : "v"(x)); return r;
}

__device__ __forceinline__ float wred(float v) {
#pragma unroll
  for (int off = 32; off > 0; off >>= 1) v += __shfl_xor(v, off, 64);
  return v;
}
__device__ __forceinline__ void wred3(float& a, float& b, float& c) {
#pragma unroll
  for (int off = 32; off > 0; off >>= 1) {
    a += __shfl_xor(a, off, 64);
    b += __shfl_xor(b, off, 64);
    c += __shfl_xor(c, off, 64);
  }
}

__device__ __forceinline__ void lse_up(float lg, float& m, float& l) {
  if (lg > m) { l = l * __expf(m - lg) + 1.0f; m = lg; }
  else l += __expf(lg - m);
}
__device__ __forceinline__ void lse_merge(float& m, float& l, float mo, float lo) {
  float mn = fmaxf(m, mo);
  l = l * __expf(m - mn) + lo * __expf(mo - mn);
  m = mn;
}

// XLA ErfInv32 (Giles)
__device__ __forceinline__ float erfinv_f(float x) {
  float w = -__logf(fmaxf(fmaf(-x, x, 1.0f), 1e-37f));
  float p;
  if (w < 5.0f) {
    w -= 2.5f;
    p = 2.81022636e-08f;
    p = fmaf(p, w, 3.43273939e-07f);
    p = fmaf(p, w, -3.5233877e-06f);
    p = fmaf(p, w, -4.39150654e-06f);
    p = fmaf(p, w, 0.00021858087f);
    p = fmaf(p, w, -0.00125372503f);
    p = fmaf(p, w, -0.00417768164f);
    p = fmaf(p, w, 0.246640727f);
    p = fmaf(p, w, 1.50140941f);
  } else {
    w = sqrtf(w) - 3.0f;
    p = -0.000200214257f;
    p = fmaf(p, w, 0.000100950558f);
    p = fmaf(p, w, 0.00134934322f);
    p = fmaf(p, w, -0.00367342844f);
    p = fmaf(p, w, 0.00573950773f);
    p = fmaf(p, w, -0.0076224613f);
    p = fmaf(p, w, 0.00943887047f);
    p = fmaf(p, w, 1.00167406f);
    p = fmaf(p, w, 2.83297682f);
  }
  return p * x;
}

// ---------------- K1: keys (block 0) + class id + hard flag + per-block counts ----------------
__global__ __launch_bounds__(256) void k_classify(const float* __restrict__ label,
    const float* __restrict__ mask, const float* __restrict__ prob,
    uint32_t* __restrict__ keys, int* __restrict__ cls, int* __restrict__ hrd,
    int* __restrict__ bcv, int* __restrict__ bch) {
  __shared__ int hv[S_], hh[S_];
  int t = threadIdx.x;
  if (t < S_) { hv[t] = 0; hh[t] = 0; }
  if (blockIdx.x == 0 && t < S_) {
    uint32_t f0, f1;
    tf2x32(0u, 1234u, 0u, (uint32_t)t, f0, f1);
#pragma unroll
    for (int k = 0; k < 4; ++k) {
      uint32_t a, b;
      tf2x32(f0, f1, 0u, (uint32_t)k, a, b);
      keys[t * 8 + k * 2] = a; keys[t * 8 + k * 2 + 1] = b;
    }
  }
  __syncthreads();
  int p = blockIdx.x * 256 + t;
  int b = p >> 14, rem = p & (HW_ - 1);
  int sp = -1;
#pragma unroll
  for (int s = 0; s < S_; ++s) {
    float l = label[((b * S_ + s) << 14) + rem];
    if (l > 0.5f) sp = s;
  }
  if (mask[(b << 14) + rem] <= 0.5f) sp = -1;
  int h = 0;
  if (sp >= 0) h = (prob[((b * S_ + sp) << 14) + rem] < 0.97f) ? 1 : 0;
  cls[p] = sp; hrd[p] = h;
  if (sp >= 0) { atomicAdd(&hv[sp], 1); if (h) atomicAdd(&hh[sp], 1); }
  __syncthreads();
  if (t < S_) { bcv[t * 256 + blockIdx.x] = hv[t]; bch[t * 256 + blockIdx.x] = hh[t]; }
}

// ---------------- K1a: per-pixel mu norm (exact f32) ----------------
__global__ __launch_bounds__(256) void k_norm(const float* __restrict__ mu,
    float2* __restrict__ rnrm) {
  int p = blockIdx.x * 256 + threadIdx.x;
  int b = p >> 14, rem = p & (HW_ - 1);
  const float* base = mu + (((size_t)(b * C_)) << 14) + rem;
  float s2 = 0.f;
#pragma unroll 4
  for (int c = 0; c < C_; ++c) {
    float v = base[(size_t)c << 14];
    s2 = fmaf(v, v, s2);
  }
  float nrm = sqrtf(s2);
  rnrm[p] = make_float2(fastrcp(fmaxf(nrm, 1e-12f)), nrm);
}

// ---------------- K1b: pack (B,C,H,W) f32 -> (P,C) fp8 {muhat, sg} interleaved ----------------
__global__ __launch_bounds__(256) void k_pack(const float* __restrict__ mu,
    const float* __restrict__ sg, const float2* __restrict__ rnrm,
    uint32_t* __restrict__ pair8) {
  __shared__ float smu[64][65];
  __shared__ float ssg[64][65];
  __shared__ float srn[64];
  int p0 = blockIdx.x * 64, c0 = blockIdx.y * 64;
  int b = p0 >> 14, rem0 = p0 & (HW_ - 1);
  if (threadIdx.x < 64) srn[threadIdx.x] = rnrm[p0 + threadIdx.x].x;
  int px = threadIdx.x & 63, cy = threadIdx.x >> 6;
#pragma unroll
  for (int itr = 0; itr < 16; ++itr) {
    int cl = cy + itr * 4;
    int addr = ((b * C_ + c0 + cl) << 14) + rem0 + px;
    smu[cl][px] = mu[addr];
    ssg[cl][px] = sg[addr];
  }
  __syncthreads();
#pragma unroll
  for (int itr = 0; itr < 8; ++itr) {
    int e = itr * 256 + threadIdx.x;
    int pxl = e >> 5, dw = e & 31, cl = dw * 2;
    float rn = srn[pxl];
    uint32_t wd = pk8<0>(smu[cl][pxl] * rn, ssg[cl][pxl], 0u);
    wd = pk8<1>(smu[cl + 1][pxl] * rn, ssg[cl + 1][pxl], wd);
    pair8[(size_t)(p0 + pxl) * 128 + (c0 >> 1) + dw] = wd;
  }
}

// parallel two-level scan: 304 workers of 16-entry chunks
__global__ __launch_bounds__(320) void k_scan(const int* __restrict__ bcv, const int* __restrict__ bch,
    int* __restrict__ bov, int* __restrict__ boh,
    int* __restrict__ cntv, int* __restrict__ cnth,
    int* __restrict__ basev, int* __restrict__ baseh) {
  __shared__ int psv[S_][16], psh[S_][16], scv[S_], sch[S_];
  int t = threadIdx.x;
  int s = t >> 4, c = t & 15;
  if (t < 304) {
    int sv = 0, sh = 0;
#pragma unroll 4
    for (int b = 0; b < 16; ++b) {
      sv += bcv[s * 256 + c * 16 + b];
      sh += bch[s * 256 + c * 16 + b];
    }
    psv[s][c] = sv; psh[s][c] = sh;
  }
  __syncthreads();
  if (t < S_) {
    int rv = 0, rh = 0;
#pragma unroll
    for (int cc = 0; cc < 16; ++cc) {
      int tv = psv[t][cc]; psv[t][cc] = rv; rv += tv;
      int th = psh[t][cc]; psh[t][cc] = rh; rh += th;
    }
    cntv[t] = rv; cnth[t] = rh; scv[t] = rv; sch[t] = rh;
  }
  __syncthreads();
  if (t == 0) {
    int bv = 0, bh = 0;
    for (int k = 0; k < S_; ++k) { basev[k] = bv; bv += scv[k]; baseh[k] = bh; bh += sch[k]; }
  }
  if (t < 304) {
    int rv = psv[s][c], rh = psh[s][c];
#pragma unroll 4
    for (int b = 0; b < 16; ++b) {
      int i0 = s * 256 + c * 16 + b;
      int tv = bcv[i0]; bov[i0] = rv; rv += tv;
      int th = bch[i0]; boh[i0] = rh; rh += th;
    }
  }
}

__global__ __launch_bounds__(256) void k_fill(const int* __restrict__ cls, const int* __restrict__ hrd,
    const int* __restrict__ bov, const int* __restrict__ boh,
    const int* __restrict__ basev, const int* __restrict__ baseh,
    int* __restrict__ posv, int* __restrict__ posh) {
  __shared__ int lc[256], lh[256];
  int t = threadIdx.x;
  int p = blockIdx.x * 256 + t;
  int s = cls[p]; int h = hrd[p];
  lc[t] = s; lh[t] = h;
  __syncthreads();
  if (s >= 0) {
    int rv = 0, rh = 0;
    for (int k = 0; k < t; ++k) { if (lc[k] == s) { rv++; rh += lh[k]; } }
    posv[basev[s] + bov[s * 256 + blockIdx.x] + rv] = p;
    if (h) posh[baseh[s] + boh[s * 256 + blockIdx.x] + rh] = p;
  }
}

// ---------------- K3: per-class partial sums (muhat * nrm restores raw mu) ----------------
__global__ __launch_bounds__(256) void k_sums(const uint32_t* __restrict__ pair8,
    const float2* __restrict__ rnrm, const int* __restrict__ cls, float* __restrict__ part) {
  __shared__ float lacc[S_][2][C_];
  __shared__ int scls[256];
  __shared__ float snrm[256];
  int t = threadIdx.x;
  for (int e = t; e < S_ * 2 * C_; e += 256) (&lacc[0][0][0])[e] = 0.f;
  int p0 = blockIdx.x * 256;
  scls[t] = cls[p0 + t];
  snrm[t] = rnrm[p0 + t].y;
  __syncthreads();
  int half = t & 1, dwi = t >> 1;
  uint32_t d = pair8[(size_t)p0 * 128 + dwi];
  for (int pp = 0; pp < 256; ++pp) {
    uint32_t dnx = (pp + 1 < 256) ? pair8[(size_t)(p0 + pp + 1) * 128 + dwi] : 0u;
    int s = scls[pp];
    if (s >= 0) {
      v2f e = half ? cvt8<1>(d) : cvt8<0>(d);
      float ia = fastrcp(e.y);
      lacc[s][0][t] += ia;
      lacc[s][1][t] += ia * e.x * snrm[pp];
    }
    d = dnx;
  }
  __syncthreads();
  float* dst = part + (size_t)blockIdx.x * (2 * S_ * C_);
  for (int e = t; e < S_ * 2 * C_; e += 256) dst[e] = (&lacc[0][0][0])[e];
}

// ---------------- K4: prototypes (reduce partials here) ----------------
__global__ __launch_bounds__(256) void k_proto(const float* __restrict__ part,
    const float* __restrict__ mmu, const float* __restrict__ msg,
    float* __restrict__ pmu, float* __restrict__ psig, float* __restrict__ phat) {
  int s = blockIdx.x, c = threadIdx.x;
  float A = 0.f, Bv = 0.f;
  for (int b = 0; b < 256; ++b) {
    const float* pb = part + (size_t)b * (2 * S_ * C_) + (s * 2) * C_;
    A += pb[c];
    Bv += pb[C_ + c];
  }
  int e = s * C_ + c;
  float psb = 1.0f / A;
  float pmb = psb * Bv;
  float ms = msg[e], mm = mmu[e];
  float ps = 1.0f / (1.0f / psb + 1.0f / ms);
  float pm = ps * (mm / ms + pmb / psb);
  pmu[e] = pm; psig[e] = ps;
  __shared__ float red[4];
  float w = wred(pm * pm);
  int lane = c & 63, wv = c >> 6;
  if (lane == 0) red[wv] = w;
  __syncthreads();
  float tot = red[0] + red[1] + red[2] + red[3];
  float nrm = fmaxf(sqrtf(tot), 1e-12f);
  phat[e] = pm / nrm;
}

// ---------------- K5a: sim -> log_softmax ----------------
__global__ __launch_bounds__(64) void k_simlogp(const float* __restrict__ phat,
    const float* __restrict__ psig, float* __restrict__ logp) {
  int i = blockIdx.x, lane = threadIdx.x;
  int c0 = lane * 4;
  float phi[4], psi[4];
#pragma unroll
  for (int k = 0; k < 4; ++k) { phi[k] = phat[i * C_ + c0 + k]; psi[k] = psig[i * C_ + c0 + k]; }
  float xs[18];
#pragma unroll
  for (int j = 0; j < 18; ++j) {
    int o = i + 1 + j; if (o >= S_) o -= S_;
    float t = 0.f;
#pragma unroll
    for (int k = 0; k < 4; ++k) {
      float d = phi[k] - phat[o * C_ + c0 + k];
      float dn = psi[k] + psig[o * C_ + c0 + k];
      t += d * d / dn + logf(dn);
    }
    t = wred(t);
    xs[j] = (-0.5f * t * (1.0f / 256.0f)) * 2.0f;
  }
  float m = xs[0];
#pragma unroll
  for (int j = 1; j < 18; ++j) m = fmaxf(m, xs[j]);
  float se = 0.f;
#pragma unroll
  for (int j = 0; j < 18; ++j) se += expf(xs[j] - m);
  float lg = logf(se);
  if (lane == 0) {
#pragma unroll
    for (int j = 0; j < 18; ++j) logp[i * 18 + j] = xs[j] - m - lg;
  }
}

// ---------------- K5c: generalized prototypes ----------------
__global__ __launch_bounds__(256) void k_gen(const uint32_t* __restrict__ keys,
    const float* __restrict__ pmu, const float* __restrict__ psig, float* __restrict__ ghat) {
  int v = blockIdx.x, i = blockIdx.y, c = threadIdx.x;
  int o = i + 1 + (v >> 3); if (o >= S_) o -= S_;
  uint32_t k0 = keys[i * 8 + 6], k1 = keys[i * 8 + 7];
  uint32_t bits = rbits(k0, k1, (uint32_t)(v * C_ + c));
  float f01 = bits2f01(bits);
  const float lo = -0.99999994f;
  float u = fmaxf(f01 * 2.0f + lo, lo);
  float eps = 1.41421356237f * erfinv_f(u);
  float g = pmu[o * C_ + c] + sqrtf(psig[o * C_ + c]) * eps;
  __shared__ float red[4];
  float w = wred(g * g);
  int lane = c & 63, wv = c >> 6;
  if (lane == 0) red[wv] = w;
  __syncthreads();
  float tot = red[0] + red[1] + red[2] + red[3];
  float nrm = fmaxf(sqrtf(tot), 1e-12f);
  ghat[((size_t)(i * GENV_ + v)) * C_ + c] = g / nrm;
}

// ---------------- K5b: class + negative sampling (gumbel argmax -> scaled-min) ----------------
__global__ __launch_bounds__(256) void k_sample(const uint32_t* __restrict__ keys,
    const float* __restrict__ logp, const int* __restrict__ cntv, const int* __restrict__ basev,
    const int* __restrict__ posv, int* __restrict__ nidx) {
  int i = blockIdx.y;
  int m = blockIdx.x * 256 + threadIdx.x;
  __shared__ float elp[18];
  __shared__ int lcnt[S_], lbase[S_];
  int t = threadIdx.x;
  if (t < 18) elp[t] = __expf(-logp[i * 18 + t]);
  if (t < S_) { lcnt[t] = cntv[t]; lbase[t] = basev[t]; }
  __syncthreads();
  uint32_t kc0 = keys[i * 8 + 2], kc1 = keys[i * 8 + 3];
  uint32_t kn0 = keys[i * 8 + 4], kn1 = keys[i * 8 + 5];
  // argmax_s( -log(-log u_s) + lp_s )  ==  argmin_s( (-log u_s) * exp(-lp_s) )
  float bv = 1e30f; int best = 0;
  for (int s = 0; s < 18; ++s) {
    uint32_t b = rbits(kc0, kc1, (uint32_t)m * 18u + (uint32_t)s);
    float u = fmaxf(bits2f01(b), 1.17549435e-38f);
    float val = (-__logf(u)) * elp[s];
    if (val < bv) { bv = val; best = s; }
  }
  float un = bits2f01(rbits(kn0, kn1, (uint32_t)m));
  int cc = i + 1 + best; if (cc >= S_) cc -= S_;
  int cnt = lcnt[cc];
  int idx = P_ - 1;
  if (cnt > 0) {
    int kk = (int)(un * (float)cnt);
    if (kk >= cnt) kk = cnt - 1;
    idx = posv[lbase[cc] + kk];
  }
  nidx[(size_t)i * NS_ + m] = idx;
}

// ---------------- K5e: bucket sort of negatives + anchor index (fused) ----------------
__global__ __launch_bounds__(64) void k_bucket(const uint32_t* __restrict__ keys,
    const int* __restrict__ cnth, const int* __restrict__ baseh, const int* __restrict__ posh,
    const int* __restrict__ nidx, int* __restrict__ snidx, int* __restrict__ boff,
    int* __restrict__ aidx) {
  int a = blockIdx.x;
  int lane = threadIdx.x;
  if (lane == 0) {
    int i = a >> 8, q = a & 255;
    uint32_t k0 = keys[i * 8 + 0], k1 = keys[i * 8 + 1];
    float u = bits2f01(rbits(k0, k1, (uint32_t)q));
    int cnt = cnth[i];
    int idx = P_ - 1;
    if (cnt > 0) {
      int kk = (int)(u * (float)cnt);
      if (kk >= cnt) kk = cnt - 1;
      idx = posh[baseh[i] + kk];
    }
    aidx[a] = idx;
  }
  const int* src = nidx + (size_t)a * NEG_;
  int e[8], bk[8];
#pragma unroll
  for (int c = 0; c < 8; ++c) { e[c] = src[c * 64 + lane]; bk[c] = (e[c] >> 13) & 7; }
  uint32_t cnt[NBUCK];
#pragma unroll
  for (int b = 0; b < NBUCK; ++b) cnt[b] = 0;
#pragma unroll
  for (int c = 0; c < 8; ++c)
#pragma unroll
    for (int b = 0; b < NBUCK; ++b) {
      unsigned long long mb = __ballot(bk[c] == b);
      cnt[b] += (uint32_t)__popcll(mb);
    }
  uint32_t base[NBUCK]; uint32_t run = 0;
#pragma unroll
  for (int b = 0; b < NBUCK; ++b) { base[b] = run; run += cnt[b]; }
  if (lane < NBUCK) boff[a * 9 + lane] = (int)base[lane];
  if (lane == 0) boff[a * 9 + 8] = NEG_;
  uint32_t off[NBUCK];
#pragma unroll
  for (int b = 0; b < NBUCK; ++b) off[b] = 0;
  unsigned long long ltm = (1ull << lane) - 1ull;
#pragma unroll
  for (int c = 0; c < 8; ++c) {
    int pos = 0;
#pragma unroll
    for (int b = 0; b < NBUCK; ++b) {
      unsigned long long mb = __ballot(bk[c] == b);
      if (bk[c] == b) pos = (int)(base[b] + off[b] + (uint32_t)__popcll(mb & ltm));
      off[b] += (uint32_t)__popcll(mb);
    }
    snidx[(size_t)a * NEG_ + pos] = e[c];
  }
}

// ---------------- K6a: negatives — R7 structure, muhat math: (ah - nh)^2 * r ----------------
__global__ __launch_bounds__(64) void k_neg(const uint32_t* __restrict__ pair8,
    const int* __restrict__ snidx, const int* __restrict__ boff,
    const int* __restrict__ aidx, float2* __restrict__ partial) {
  __shared__ float4 anc[260];    // two regions: [0..128), [130..258) — {ah,as}x2ch per float4
  int bid = blockIdx.x;
  int bucket = bid & 7;          // XCD-affine
  int pr = bid >> 3;
  int a0 = pr * 2, a1 = a0 + 1;
  int lane = threadIdx.x;

  int ap0 = aidx[a0], ap1 = aidx[a1];
  uint2 d0 = ((const uint2*)(pair8 + (size_t)ap0 * 128))[lane];
  uint2 d1 = ((const uint2*)(pair8 + (size_t)ap1 * 128))[lane];
  {
    v2f ex = cvt8<0>(d0.x), ey = cvt8<1>(d0.x), ez = cvt8<0>(d0.y), ew = cvt8<1>(d0.y);
    anc[lane * 2]     = make_float4(ex.x, ex.y, ey.x, ey.y);
    anc[lane * 2 + 1] = make_float4(ez.x, ez.y, ew.x, ew.y);
    ex = cvt8<0>(d1.x); ey = cvt8<1>(d1.x); ez = cvt8<0>(d1.y); ew = cvt8<1>(d1.y);
    anc[130 + lane * 2]     = make_float4(ex.x, ex.y, ey.x, ey.y);
    anc[130 + lane * 2 + 1] = make_float4(ez.x, ez.y, ew.x, ew.y);
  }
  __syncthreads();

  int s0 = boff[a0 * 9 + bucket], e0i = boff[a0 * 9 + bucket + 1];
  int s1 = boff[a1 * 9 + bucket], e1i = boff[a1 * 9 + bucket + 1];
  int L0 = e0i - s0, L1 = e1i - s1, Lt = L0 + L1;
  const int* list0 = snidx + (size_t)a0 * NEG_ + s0;
  const int* list1 = snidx + (size_t)a1 * NEG_ + s1;

  float m0 = -1e30f, l0 = 0.f, m1 = -1e30f, l1 = 0.f;

  for (int r = 0; r * 64 < Lt; ++r) {
    int g = r * 64 + lane;
    bool act = g < Lt;
    int which = (act && g >= L0) ? 1 : 0;
    int j = which ? (g - L0) : g;
    int p = act ? (which ? list1[j] : list0[j]) : ap0;
    const uint4* rp = (const uint4*)(pair8 + (size_t)p * 128);
    const float4* A = anc + which * 130;
    float sT = 0.f, sL = 0.f;
    uint4 c0 = rp[0], c1 = rp[1];
#pragma unroll 1
    for (int it = 0; it < 16; ++it) {
      int nx = ((it + 1) & 15) * 2;
      uint4 n0 = rp[nx], n1 = rp[nx + 1];
      uint32_t dws[8] = {c0.x, c0.y, c0.z, c0.w, c1.x, c1.y, c1.z, c1.w};
      float pp = 1.0f, pq = 1.0f;
#pragma unroll
      for (int gq = 0; gq < 4; ++gq) {
        float4 acA = A[it * 8 + gq * 2];
        float4 acB = A[it * 8 + gq * 2 + 1];
        v2f e0v = cvt8<0>(dws[2 * gq]),     e1v = cvt8<1>(dws[2 * gq]);
        v2f e2v = cvt8<0>(dws[2 * gq + 1]), e3v = cvt8<1>(dws[2 * gq + 1]);
        float dn0 = acA.y + e0v.y, dn1 = acA.w + e1v.y;
        float dn2 = acB.y + e2v.y, dn3 = acB.w + e3v.y;
        float d01 = dn0 * dn1, d23 = dn2 * dn3;
        float R01 = fastrcp(d01), R23 = fastrcp(d23);
        pp *= d01; pq *= d23;
        float r0 = dn1 * R01, r1 = dn0 * R01, r2 = dn3 * R23, r3 = dn2 * R23;
        float f0 = acA.x - e0v.x, f1 = acA.z - e1v.x;
        float f2 = acB.x - e2v.x, f3 = acB.z - e3v.x;
        sT = fmaf(f0 * f0, r0, sT); sT = fmaf(f1 * f1, r1, sT);
        sT = fmaf(f2 * f2, r2, sT); sT = fmaf(f3 * f3, r3, sT);
      }
      sL += __logf(pp * pq);   // 16-ch product, range [0.2^16, 2^16] — safe
      c0 = n0; c1 = n1;
    }
    float lg = -(sT + sL) * (1.0f / 256.0f);
    if (act) { if (which) lse_up(lg, m1, l1); else lse_up(lg, m0, l0); }
  }
#pragma unroll
  for (int o = 32; o > 0; o >>= 1) {
    float mo = __shfl_xor(m0, o, 64), lo = __shfl_xor(l0, o, 64);
    lse_merge(m0, l0, mo, lo);
    mo = __shfl_xor(m1, o, 64); lo = __shfl_xor(l1, o, 64);
    lse_merge(m1, l1, mo, lo);
  }
  if (lane == 0) {
    partial[a0 * NBUCK + bucket] = make_float2(m0, l0);
    partial[a1 * NBUCK + bucket] = make_float2(m1, l1);
  }
}

// ---------------- K6b: pos + gens + merge partials ----------------
__global__ __launch_bounds__(256, 4) void k_fin(const uint32_t* __restrict__ pair8,
    const float* __restrict__ phat, const float* __restrict__ psig,
    const float* __restrict__ ghat, const int* __restrict__ aidx,
    const float2* __restrict__ partial, float* __restrict__ out) {
  __shared__ float2 ancG[C_];   // {w, ahat*w}
  __shared__ float redm[3][4];
  __shared__ float2 mlw[4];

  int bid = blockIdx.x;
  int i = bid >> 8;
  int t = threadIdx.x, w = t >> 6, lane = t & 63;

  int ap = aidx[bid];
  uint32_t ad = pair8[(size_t)ap * 128 + (t >> 1)];
  v2f ae0 = cvt8<0>(ad), ae1 = cvt8<1>(ad);
  float ahat = (t & 1) ? ae1.x : ae0.x;
  float asg = (t & 1) ? ae1.y : ae0.y;
  float wv = fastrcp(asg);
  ancG[t] = make_float2(wv, ahat * wv);

  float pm = phat[i * C_ + t];
  float ps = psig[i * C_ + t];
  float dnp = asg + ps;
  float dd = ahat - pm;
  float post = fmaf(dd * dd, fastrcp(dnp), __logf(dnp));
  float a1t = ahat * ahat * wv;
  float lat = __logf(asg);
  wred3(post, a1t, lat);
  if (lane == 0) { redm[0][w] = post; redm[1][w] = a1t; redm[2][w] = lat; }
  __syncthreads();
  float postS = redm[0][0] + redm[0][1] + redm[0][2] + redm[0][3];
  float Kc = (redm[1][0] + redm[1][1] + redm[1][2] + redm[1][3])
           + (redm[2][0] + redm[2][1] + redm[2][2] + redm[2][3]);
  float logit0 = -postS * (1.0f / 256.0f);

  float m = -1e30f, l = 0.0f;
  const float4* ancGf = (const float4*)ancG;
  if (lane < 36) {
    int g = lane * 4 + w;
    const float4* gp = (const float4*)(ghat + ((size_t)(i * GENV_ + g)) * C_);
    float a1 = 0.f, a2 = 0.f;
    for (int itr = 0; itr < 64; ++itr) {
      float4 gv = gp[itr];
      float4 g01 = ancGf[itr * 2];
      float4 g23 = ancGf[itr * 2 + 1];
      a1 = fmaf(gv.x * gv.x, g01.x, a1); a2 = fmaf(gv.x, g01.y, a2);
      a1 = fmaf(gv.y * gv.y, g01.z, a1); a2 = fmaf(gv.y, g01.w, a2);
      a1 = fmaf(gv.z * gv.z, g23.x, a1); a2 = fmaf(gv.z, g23.y, a2);
      a1 = fmaf(gv.w * gv.w, g23.z, a1); a2 = fmaf(gv.w, g23.w, a2);
    }
    float lg = -(Kc + a1 - 2.0f * a2) * (1.0f / 256.0f);
    lse_up(lg, m, l);
  }
#pragma unroll
  for (int o = 32; o > 0; o >>= 1) {
    float mo = __shfl_xor(m, o, 64);
    float lo = __shfl_xor(l, o, 64);
    lse_merge(m, l, mo, lo);
  }
  if (lane == 0) mlw[w] = make_float2(m, l);
  __syncthreads();
  if (t == 0) {
    float mm = mlw[0].x, ll = mlw[0].y;
    lse_merge(mm, ll, mlw[1].x, mlw[1].y);
    lse_merge(mm, ll, mlw[2].x, mlw[2].y);
    lse_merge(mm, ll, mlw[3].x, mlw[3].y);
    const float2* pp = partial + (size_t)bid * NBUCK;
#pragma unroll
    for (int b = 0; b < NBUCK; ++b) lse_merge(mm, ll, pp[b].x, pp[b].y);
    lse_merge(mm, ll, logit0, 1.0f);
    float lse = mm + __logf(ll);
    float contrib = logit0 - lse;
    atomicAdd(out, -contrib * (1.0f / (19.0f * 256.0f)));
  }
}

// ---------------- host ----------------
extern "C" void kernel_launch(void* const* d_in, const int* in_sizes, int n_in,
                              void* d_out, int out_size, void* d_ws, size_t ws_size,
                              hipStream_t stream) {
  const float* mu    = (const float*)d_in[0];
  const float* sg    = (const float*)d_in[1];
  const float* label = (const float*)d_in[2];
  const float* mask  = (const float*)d_in[3];
  const float* prob  = (const float*)d_in[4];
  const float* mmu   = (const float*)d_in[5];
  const float* msg   = (const float*)d_in[6];

  char* ws = (char*)d_ws;
  size_t off = 0;
  auto take = [&](size_t bytes) { size_t r = off; off = (off + bytes + 255) & ~(size_t)255; return r; };
  size_t o_pair8 = take((size_t)P_ * 128 * 4);   // 32 MB
  size_t o_rnrm  = take((size_t)P_ * 8);
  size_t o_cls   = take((size_t)P_ * 4);
  size_t o_hrd   = take((size_t)P_ * 4);
  size_t o_bcv   = take(S_ * 256 * 4);
  size_t o_bch   = take(S_ * 256 * 4);
  size_t o_bov   = take(S_ * 256 * 4);
  size_t o_boh   = take(S_ * 256 * 4);
  size_t o_cntv  = take(S_ * 4);
  size_t o_cnth  = take(S_ * 4);
  size_t o_basev = take(S_ * 4);
  size_t o_baseh = take(S_ * 4);
  size_t o_posv  = take((size_t)P_ * 4);
  size_t o_posh  = take((size_t)P_ * 4);
  size_t o_part  = take((size_t)256 * 2 * S_ * C_ * 4);
  size_t o_pmu   = take(S_ * C_ * 4);
  size_t o_psig  = take(S_ * C_ * 4);
  size_t o_phat  = take(S_ * C_ * 4);
  size_t o_logp  = take(S_ * 18 * 4);
  size_t o_keys  = take(S_ * 8 * 4);
  size_t o_aidx  = take(S_ * Q_ * 4);
  size_t o_nidx  = take((size_t)S_ * NS_ * 4);
  size_t o_snidx = take((size_t)S_ * NS_ * 4);
  size_t o_boff  = take((size_t)NANCH * 9 * 4);
  size_t o_lpar  = take((size_t)NANCH * NBUCK * 8);
  size_t o_ghat  = take((size_t)S_ * GENV_ * C_ * 4);
  if (ws_size < off) return;

  uint32_t* pair8 = (uint32_t*)(ws + o_pair8);
  float2*   rnrm  = (float2*)(ws + o_rnrm);
  int*      cls   = (int*)(ws + o_cls);
  int*      hrd   = (int*)(ws + o_hrd);
  int*      bcv   = (int*)(ws + o_bcv);
  int*      bch   = (int*)(ws + o_bch);
  int*      bov   = (int*)(ws + o_bov);
  int*      boh   = (int*)(ws + o_boh);
  int*      cntv  = (int*)(ws + o_cntv);
  int*      cnth  = (int*)(ws + o_cnth);
  int*      basev = (int*)(ws + o_basev);
  int*      baseh = (int*)(ws + o_baseh);
  int*      posv  = (int*)(ws + o_posv);
  int*      posh  = (int*)(ws + o_posh);
  float*    part  = (float*)(ws + o_part);
  float*    pmu   = (float*)(ws + o_pmu);
  float*    psig  = (float*)(ws + o_psig);
  float*    phat  = (float*)(ws + o_phat);
  float*    logp  = (float*)(ws + o_logp);
  uint32_t* keys  = (uint32_t*)(ws + o_keys);
  int*      aidx  = (int*)(ws + o_aidx);
  int*      nidx  = (int*)(ws + o_nidx);
  int*      snidx = (int*)(ws + o_snidx);
  int*      boff  = (int*)(ws + o_boff);
  float2*   lpar  = (float2*)(ws + o_lpar);
  float*    ghat  = (float*)(ws + o_ghat);

  hipMemsetAsync(d_out, 0, (size_t)out_size * 4, stream);

  k_classify<<<256, 256, 0, stream>>>(label, mask, prob, keys, cls, hrd, bcv, bch);
  k_norm<<<256, 256, 0, stream>>>(mu, rnrm);
  k_pack<<<dim3(P_ / 64, C_ / 64), 256, 0, stream>>>(mu, sg, rnrm, pair8);
  k_scan<<<1, 320, 0, stream>>>(bcv, bch, bov, boh, cntv, cnth, basev, baseh);
  k_fill<<<256, 256, 0, stream>>>(cls, hrd, bov, boh, basev, baseh, posv, posh);
  k_sums<<<256, 256, 0, stream>>>(pair8, rnrm, cls, part);
  k_proto<<<S_, 256, 0, stream>>>(part, mmu, msg, pmu, psig, phat);
  k_simlogp<<<S_, 64, 0, stream>>>(phat, psig, logp);
  k_gen<<<dim3(GENV_, S_), 256, 0, stream>>>(keys, pmu, psig, ghat);
  k_sample<<<dim3(512, S_), 256, 0, stream>>>(keys, logp, cntv, basev, posv, nidx);
  k_bucket<<<NANCH, 64, 0, stream>>>(keys, cnth, baseh, posh, nidx, snidx, boff, aidx);
  k_neg<<<NBUCK * NPAIR, 64, 0, stream>>>(pair8, snidx, boff, aidx, lpar);
  k_fin<<<NANCH, 256, 0, stream>>>(pair8, phat, psig, ghat, aidx, lpar, (float*)d_out);
}

// Round 10
// 604.124 us; speedup vs baseline: 1.2861x; 1.0199x over previous
//
#include <hip/hip_runtime.h>
#include <hip/hip_fp16.h>
#include <hip/hip_fp8.h>
#include <cstdint>

#define B_   4
#define S_   19
#define HW_  16384
#define P_   65536
#define C_   256
#define Q_   256
#define NEG_ 512
#define NS_  131072
#define GENV_ 144
#define NANCH (S_ * 256)     // 4864
#define NPAIR (NANCH / 2)    // 2432
#define NBUCK 8

typedef float v2f __attribute__((ext_vector_type(2)));

#if __has_builtin(__builtin_amdgcn_cvt_pk_f32_fp8) && __has_builtin(__builtin_amdgcn_cvt_pk_fp8_f32)
#define HAVE_HW_FP8 1
#endif

template<int W> __device__ __forceinline__ v2f cvt8(uint32_t d) {
#ifdef HAVE_HW_FP8
  v2f r = __builtin_amdgcn_cvt_pk_f32_fp8((int)d, W);
  return r;
#else
  __hip_fp8_e4m3 h0, h1;
  h0.__x = (uint8_t)(d >> (W * 16));
  h1.__x = (uint8_t)(d >> (W * 16 + 8));
  v2f r; r.x = (float)h0; r.y = (float)h1; return r;
#endif
}
template<int W> __device__ __forceinline__ uint32_t pk8(float a, float b, uint32_t old) {
#ifdef HAVE_HW_FP8
  return (uint32_t)__builtin_amdgcn_cvt_pk_fp8_f32(a, b, (int)old, W);
#else
  __hip_fp8_e4m3 ha(a), hb(b);
  uint32_t v = (uint32_t)ha.__x | ((uint32_t)hb.__x << 8);
  return (old & (W ? 0x0000FFFFu : 0xFFFF0000u)) | (v << (W * 16));
#endif
}

// ---------------- threefry2x32 (JAX-exact) ----------------
__device__ __forceinline__ void tf2x32(uint32_t k0, uint32_t k1, uint32_t x0, uint32_t x1,
                                       uint32_t& o0, uint32_t& o1) {
  uint32_t k2 = k0 ^ k1 ^ 0x1BD11BDAu;
#define TFR(r) { x0 += x1; x1 = (x1 << r) | (x1 >> (32 - r)); x1 ^= x0; }
  x0 += k0; x1 += k1;
  TFR(13) TFR(15) TFR(26) TFR(6)  x0 += k1; x1 += k2 + 1u;
  TFR(17) TFR(29) TFR(16) TFR(24) x0 += k2; x1 += k0 + 2u;
  TFR(13) TFR(15) TFR(26) TFR(6)  x0 += k0; x1 += k1 + 3u;
  TFR(17) TFR(29) TFR(16) TFR(24) x0 += k1; x1 += k2 + 4u;
  TFR(13) TFR(15) TFR(26) TFR(6)  x0 += k2; x1 += k0 + 5u;
#undef TFR
  o0 = x0; o1 = x1;
}

__device__ __forceinline__ uint32_t rbits(uint32_t k0, uint32_t k1, uint32_t n) {
  uint32_t a, b; tf2x32(k0, k1, 0u, n, a, b); return a ^ b;
}

__device__ __forceinline__ float bits2f01(uint32_t b) {
  return __uint_as_float((b >> 9) | 0x3f800000u) - 1.0f;
}

__device__ __forceinline__ float fastrcp(float x) {
  float r; asm("v_rcp_f32 %0, %1" : "=v"(r) : "v"(x)); return r;
}

__device__ __forceinline__ float wred(float v) {
#pragma unroll
  for (int off = 32; off > 0; off >>= 1) v += __shfl_xor(v, off, 64);
  return v;
}
__device__ __forceinline__ void wred3(float& a, float& b, float& c) {
#pragma unroll
  for (int off = 32; off > 0; off >>= 1) {
    a += __shfl_xor(a, off, 64);
    b += __shfl_xor(b, off, 64);
    c += __shfl_xor(c, off, 64);
  }
}

__device__ __forceinline__ void lse_up(float lg, float& m, float& l) {
  if (lg > m) { l = l * __expf(m - lg) + 1.0f; m = lg; }
  else l += __expf(lg - m);
}
__device__ __forceinline__ void lse_merge(float& m, float& l, float mo, float lo) {
  float mn = fmaxf(m, mo);
  l = l * __expf(m - mn) + lo * __expf(mo - mn);
  m = mn;
}

// XLA ErfInv32 (Giles)
__device__ __forceinline__ float erfinv_f(float x) {
  float w = -__logf(fmaxf(fmaf(-x, x, 1.0f), 1e-37f));
  float p;
  if (w < 5.0f) {
    w -= 2.5f;
    p = 2.81022636e-08f;
    p = fmaf(p, w, 3.43273939e-07f);
    p = fmaf(p, w, -3.5233877e-06f);
    p = fmaf(p, w, -4.39150654e-06f);
    p = fmaf(p, w, 0.00021858087f);
    p = fmaf(p, w, -0.00125372503f);
    p = fmaf(p, w, -0.00417768164f);
    p = fmaf(p, w, 0.246640727f);
    p = fmaf(p, w, 1.50140941f);
  } else {
    w = sqrtf(w) - 3.0f;
    p = -0.000200214257f;
    p = fmaf(p, w, 0.000100950558f);
    p = fmaf(p, w, 0.00134934322f);
    p = fmaf(p, w, -0.00367342844f);
    p = fmaf(p, w, 0.00573950773f);
    p = fmaf(p, w, -0.0076224613f);
    p = fmaf(p, w, 0.00943887047f);
    p = fmaf(p, w, 1.00167406f);
    p = fmaf(p, w, 2.83297682f);
  }
  return p * x;
}

// ---------------- K1: keys (block 0) + class/hard + per-block counts + mu norm ----------------
__global__ __launch_bounds__(256) void k_classify(const float* __restrict__ label,
    const float* __restrict__ mask, const float* __restrict__ prob,
    const float* __restrict__ mu,
    uint32_t* __restrict__ keys, int* __restrict__ cls, int* __restrict__ hrd,
    int* __restrict__ bcv, int* __restrict__ bch, float2* __restrict__ rnrm) {
  __shared__ int hv[S_], hh[S_];
  int t = threadIdx.x;
  if (t < S_) { hv[t] = 0; hh[t] = 0; }
  if (blockIdx.x == 0 && t < S_) {
    uint32_t f0, f1;
    tf2x32(0u, 1234u, 0u, (uint32_t)t, f0, f1);
#pragma unroll
    for (int k = 0; k < 4; ++k) {
      uint32_t a, b;
      tf2x32(f0, f1, 0u, (uint32_t)k, a, b);
      keys[t * 8 + k * 2] = a; keys[t * 8 + k * 2 + 1] = b;
    }
  }
  __syncthreads();
  int p = blockIdx.x * 256 + t;
  int b = p >> 14, rem = p & (HW_ - 1);
  int sp = -1;
#pragma unroll
  for (int s = 0; s < S_; ++s) {
    float l = label[((b * S_ + s) << 14) + rem];
    if (l > 0.5f) sp = s;
  }
  if (mask[(b << 14) + rem] <= 0.5f) sp = -1;
  int h = 0;
  if (sp >= 0) h = (prob[((b * S_ + sp) << 14) + rem] < 0.97f) ? 1 : 0;
  cls[p] = sp; hrd[p] = h;
  if (sp >= 0) { atomicAdd(&hv[sp], 1); if (h) atomicAdd(&hh[sp], 1); }
  __syncthreads();
  if (t < S_) { bcv[t * 256 + blockIdx.x] = hv[t]; bch[t * 256 + blockIdx.x] = hh[t]; }
  // ---- fused: per-pixel mu norm (exact f32) ----
  const float* basep = mu + (((size_t)(b * C_)) << 14) + rem;
  float s2 = 0.f;
#pragma unroll 8
  for (int c = 0; c < C_; ++c) {
    float v = basep[(size_t)c << 14];
    s2 = fmaf(v, v, s2);
  }
  float nrm = sqrtf(s2);
  rnrm[p] = make_float2(fastrcp(fmaxf(nrm, 1e-12f)), nrm);
}

// ---------------- K1b: pack (B,C,H,W) f32 -> (P,C) fp8 {muhat, sg} interleaved ----------------
__global__ __launch_bounds__(256) void k_pack(const float* __restrict__ mu,
    const float* __restrict__ sg, const float2* __restrict__ rnrm,
    uint32_t* __restrict__ pair8) {
  __shared__ float smu[64][65];
  __shared__ float ssg[64][65];
  __shared__ float srn[64];
  int p0 = blockIdx.x * 64, c0 = blockIdx.y * 64;
  int b = p0 >> 14, rem0 = p0 & (HW_ - 1);
  if (threadIdx.x < 64) srn[threadIdx.x] = rnrm[p0 + threadIdx.x].x;
  int px = threadIdx.x & 63, cy = threadIdx.x >> 6;
#pragma unroll
  for (int itr = 0; itr < 16; ++itr) {
    int cl = cy + itr * 4;
    int addr = ((b * C_ + c0 + cl) << 14) + rem0 + px;
    smu[cl][px] = mu[addr];
    ssg[cl][px] = sg[addr];
  }
  __syncthreads();
#pragma unroll
  for (int itr = 0; itr < 8; ++itr) {
    int e = itr * 256 + threadIdx.x;
    int pxl = e >> 5, dw = e & 31, cl = dw * 2;
    float rn = srn[pxl];
    uint32_t wd = pk8<0>(smu[cl][pxl] * rn, ssg[cl][pxl], 0u);
    wd = pk8<1>(smu[cl + 1][pxl] * rn, ssg[cl + 1][pxl], wd);
    pair8[(size_t)(p0 + pxl) * 128 + (c0 >> 1) + dw] = wd;
  }
}

// parallel two-level scan: 304 workers of 16-entry chunks
__global__ __launch_bounds__(320) void k_scan(const int* __restrict__ bcv, const int* __restrict__ bch,
    int* __restrict__ bov, int* __restrict__ boh,
    int* __restrict__ cntv, int* __restrict__ cnth,
    int* __restrict__ basev, int* __restrict__ baseh) {
  __shared__ int psv[S_][16], psh[S_][16], scv[S_], sch[S_];
  int t = threadIdx.x;
  int s = t >> 4, c = t & 15;
  if (t < 304) {
    int sv = 0, sh = 0;
#pragma unroll 4
    for (int b = 0; b < 16; ++b) {
      sv += bcv[s * 256 + c * 16 + b];
      sh += bch[s * 256 + c * 16 + b];
    }
    psv[s][c] = sv; psh[s][c] = sh;
  }
  __syncthreads();
  if (t < S_) {
    int rv = 0, rh = 0;
#pragma unroll
    for (int cc = 0; cc < 16; ++cc) {
      int tv = psv[t][cc]; psv[t][cc] = rv; rv += tv;
      int th = psh[t][cc]; psh[t][cc] = rh; rh += th;
    }
    cntv[t] = rv; cnth[t] = rh; scv[t] = rv; sch[t] = rh;
  }
  __syncthreads();
  if (t == 0) {
    int bv = 0, bh = 0;
    for (int k = 0; k < S_; ++k) { basev[k] = bv; bv += scv[k]; baseh[k] = bh; bh += sch[k]; }
  }
  if (t < 304) {
    int rv = psv[s][c], rh = psh[s][c];
#pragma unroll 4
    for (int b = 0; b < 16; ++b) {
      int i0 = s * 256 + c * 16 + b;
      int tv = bcv[i0]; bov[i0] = rv; rv += tv;
      int th = bch[i0]; boh[i0] = rh; rh += th;
    }
  }
}

// ---------------- K2: fused fill (pos lists) + per-class partial sums ----------------
__global__ __launch_bounds__(256) void k_fillsums(const uint32_t* __restrict__ pair8,
    const float2* __restrict__ rnrm, const int* __restrict__ cls, const int* __restrict__ hrd,
    const int* __restrict__ bov, const int* __restrict__ boh,
    const int* __restrict__ basev, const int* __restrict__ baseh,
    int* __restrict__ posv, int* __restrict__ posh, float* __restrict__ part) {
  __shared__ float lacc[S_][2][C_];   // 38 KB
  __shared__ int scls[256];
  __shared__ int slh[256];
  __shared__ float snrm[256];
  int t = threadIdx.x;
  int p0 = blockIdx.x * 256;
  int p = p0 + t;
  int s = cls[p]; int h = hrd[p];
  scls[t] = s; slh[t] = h;
  snrm[t] = rnrm[p].y;
  for (int e = t; e < S_ * 2 * C_; e += 256) (&lacc[0][0][0])[e] = 0.f;
  __syncthreads();
  // ---- fill: stable rank within block ----
  if (s >= 0) {
    int rv = 0, rh = 0;
    for (int k = 0; k < t; ++k) { if (scls[k] == s) { rv++; rh += slh[k]; } }
    posv[basev[s] + bov[s * 256 + blockIdx.x] + rv] = p;
    if (h) posh[baseh[s] + boh[s * 256 + blockIdx.x] + rh] = p;
  }
  // ---- sums: thread owns channel t (column of lacc) ----
  int half = t & 1, dwi = t >> 1;
  uint32_t d = pair8[(size_t)p0 * 128 + dwi];
  for (int pp = 0; pp < 256; ++pp) {
    uint32_t dnx = (pp + 1 < 256) ? pair8[(size_t)(p0 + pp + 1) * 128 + dwi] : 0u;
    int sc = scls[pp];
    if (sc >= 0) {
      v2f e = half ? cvt8<1>(d) : cvt8<0>(d);
      float ia = fastrcp(e.y);
      lacc[sc][0][t] += ia;
      lacc[sc][1][t] += ia * e.x * snrm[pp];
    }
    d = dnx;
  }
  __syncthreads();
  float* dst = part + (size_t)blockIdx.x * (2 * S_ * C_);
  for (int e = t; e < S_ * 2 * C_; e += 256) dst[e] = (&lacc[0][0][0])[e];
}

// ---------------- K4: prototypes — 1024 threads, 4-way reduction over part blocks ----------------
__global__ __launch_bounds__(1024) void k_proto(const float* __restrict__ part,
    const float* __restrict__ mmu, const float* __restrict__ msg,
    float* __restrict__ pmu, float* __restrict__ psig, float* __restrict__ phat) {
  __shared__ float redA[4][C_];
  __shared__ float redB[4][C_];
  __shared__ float red[4];
  int s = blockIdx.x;
  int t = threadIdx.x;
  int c = t & 255, grp = t >> 8;
  float A = 0.f, Bv = 0.f;
  for (int b = grp * 64; b < grp * 64 + 64; ++b) {
    const float* pb = part + (size_t)b * (2 * S_ * C_) + (s * 2) * C_;
    A += pb[c];
    Bv += pb[C_ + c];
  }
  redA[grp][c] = A; redB[grp][c] = Bv;
  __syncthreads();
  float pm = 0.f;
  if (grp == 0) {
    A = redA[0][c] + redA[1][c] + redA[2][c] + redA[3][c];
    Bv = redB[0][c] + redB[1][c] + redB[2][c] + redB[3][c];
    int e = s * C_ + c;
    float psb = 1.0f / A;
    float pmb = psb * Bv;
    float ms = msg[e], mm = mmu[e];
    float ps = 1.0f / (1.0f / psb + 1.0f / ms);
    pm = ps * (mm / ms + pmb / psb);
    pmu[e] = pm; psig[e] = ps;
    float w = wred(pm * pm);
    int lane = c & 63, wv = c >> 6;
    if (lane == 0) red[wv] = w;
  }
  __syncthreads();
  if (grp == 0) {
    float tot = red[0] + red[1] + red[2] + red[3];
    float nrm = fmaxf(sqrtf(tot), 1e-12f);
    phat[s * C_ + c] = pm / nrm;
  }
}

// ---------------- K5a: sim -> log_softmax ----------------
__global__ __launch_bounds__(64) void k_simlogp(const float* __restrict__ phat,
    const float* __restrict__ psig, float* __restrict__ logp) {
  int i = blockIdx.x, lane = threadIdx.x;
  int c0 = lane * 4;
  float phi[4], psi[4];
#pragma unroll
  for (int k = 0; k < 4; ++k) { phi[k] = phat[i * C_ + c0 + k]; psi[k] = psig[i * C_ + c0 + k]; }
  float xs[18];
#pragma unroll
  for (int j = 0; j < 18; ++j) {
    int o = i + 1 + j; if (o >= S_) o -= S_;
    float t = 0.f;
#pragma unroll
    for (int k = 0; k < 4; ++k) {
      float d = phi[k] - phat[o * C_ + c0 + k];
      float dn = psi[k] + psig[o * C_ + c0 + k];
      t += d * d / dn + logf(dn);
    }
    t = wred(t);
    xs[j] = (-0.5f * t * (1.0f / 256.0f)) * 2.0f;
  }
  float m = xs[0];
#pragma unroll
  for (int j = 1; j < 18; ++j) m = fmaxf(m, xs[j]);
  float se = 0.f;
#pragma unroll
  for (int j = 0; j < 18; ++j) se += expf(xs[j] - m);
  float lg = logf(se);
  if (lane == 0) {
#pragma unroll
    for (int j = 0; j < 18; ++j) logp[i * 18 + j] = xs[j] - m - lg;
  }
}

// ---------------- K5bc: fused generalized prototypes + class/negative sampling ----------------
__global__ __launch_bounds__(256) void k_gensample(const uint32_t* __restrict__ keys,
    const float* __restrict__ pmu, const float* __restrict__ psig,
    const float* __restrict__ logp, const int* __restrict__ cntv, const int* __restrict__ basev,
    const int* __restrict__ posv, float* __restrict__ ghat, int* __restrict__ nidx) {
  __shared__ float red[4];
  __shared__ float elp[18];
  __shared__ int lcnt[S_], lbase[S_];
  int bid = blockIdx.x;
  int t = threadIdx.x;
  if (bid < GENV_ * S_) {
    // ---- gen ----
    int v = bid % GENV_, i = bid / GENV_;
    int c = t;
    int o = i + 1 + (v >> 3); if (o >= S_) o -= S_;
    uint32_t k0 = keys[i * 8 + 6], k1 = keys[i * 8 + 7];
    uint32_t bits = rbits(k0, k1, (uint32_t)(v * C_ + c));
    float f01 = bits2f01(bits);
    const float lo = -0.99999994f;
    float u = fmaxf(f01 * 2.0f + lo, lo);
    float eps = 1.41421356237f * erfinv_f(u);
    float g = pmu[o * C_ + c] + sqrtf(psig[o * C_ + c]) * eps;
    float w = wred(g * g);
    int lane = c & 63, wv = c >> 6;
    if (lane == 0) red[wv] = w;
    __syncthreads();
    float tot = red[0] + red[1] + red[2] + red[3];
    float nrm = fmaxf(sqrtf(tot), 1e-12f);
    ghat[((size_t)(i * GENV_ + v)) * C_ + c] = g / nrm;
  } else {
    // ---- sample ----
    int sid = bid - GENV_ * S_;
    int i = sid / 512;
    int m = (sid % 512) * 256 + t;
    if (t < 18) elp[t] = __expf(-logp[i * 18 + t]);
    if (t < S_) { lcnt[t] = cntv[t]; lbase[t] = basev[t]; }
    __syncthreads();
    uint32_t kc0 = keys[i * 8 + 2], kc1 = keys[i * 8 + 3];
    uint32_t kn0 = keys[i * 8 + 4], kn1 = keys[i * 8 + 5];
    // argmax_s( -log(-log u_s) + lp_s ) == argmin_s( (-log u_s) * exp(-lp_s) )
    float bv = 1e30f; int best = 0;
    for (int s = 0; s < 18; ++s) {
      uint32_t b = rbits(kc0, kc1, (uint32_t)m * 18u + (uint32_t)s);
      float u = fmaxf(bits2f01(b), 1.17549435e-38f);
      float val = (-__logf(u)) * elp[s];
      if (val < bv) { bv = val; best = s; }
    }
    float un = bits2f01(rbits(kn0, kn1, (uint32_t)m));
    int cc = i + 1 + best; if (cc >= S_) cc -= S_;
    int cnt = lcnt[cc];
    int idx = P_ - 1;
    if (cnt > 0) {
      int kk = (int)(un * (float)cnt);
      if (kk >= cnt) kk = cnt - 1;
      idx = posv[lbase[cc] + kk];
    }
    nidx[(size_t)i * NS_ + m] = idx;
  }
}

// ---------------- K5e: bucket sort of negatives + anchor index (fused) ----------------
__global__ __launch_bounds__(64) void k_bucket(const uint32_t* __restrict__ keys,
    const int* __restrict__ cnth, const int* __restrict__ baseh, const int* __restrict__ posh,
    const int* __restrict__ nidx, int* __restrict__ snidx, int* __restrict__ boff,
    int* __restrict__ aidx) {
  int a = blockIdx.x;
  int lane = threadIdx.x;
  if (lane == 0) {
    int i = a >> 8, q = a & 255;
    uint32_t k0 = keys[i * 8 + 0], k1 = keys[i * 8 + 1];
    float u = bits2f01(rbits(k0, k1, (uint32_t)q));
    int cnt = cnth[i];
    int idx = P_ - 1;
    if (cnt > 0) {
      int kk = (int)(u * (float)cnt);
      if (kk >= cnt) kk = cnt - 1;
      idx = posh[baseh[i] + kk];
    }
    aidx[a] = idx;
  }
  const int* src = nidx + (size_t)a * NEG_;
  int e[8], bk[8];
#pragma unroll
  for (int c = 0; c < 8; ++c) { e[c] = src[c * 64 + lane]; bk[c] = (e[c] >> 13) & 7; }
  uint32_t cnt[NBUCK];
#pragma unroll
  for (int b = 0; b < NBUCK; ++b) cnt[b] = 0;
#pragma unroll
  for (int c = 0; c < 8; ++c)
#pragma unroll
    for (int b = 0; b < NBUCK; ++b) {
      unsigned long long mb = __ballot(bk[c] == b);
      cnt[b] += (uint32_t)__popcll(mb);
    }
  uint32_t base[NBUCK]; uint32_t run = 0;
#pragma unroll
  for (int b = 0; b < NBUCK; ++b) { base[b] = run; run += cnt[b]; }
  if (lane < NBUCK) boff[a * 9 + lane] = (int)base[lane];
  if (lane == 0) boff[a * 9 + 8] = NEG_;
  uint32_t off[NBUCK];
#pragma unroll
  for (int b = 0; b < NBUCK; ++b) off[b] = 0;
  unsigned long long ltm = (1ull << lane) - 1ull;
#pragma unroll
  for (int c = 0; c < 8; ++c) {
    int pos = 0;
#pragma unroll
    for (int b = 0; b < NBUCK; ++b) {
      unsigned long long mb = __ballot(bk[c] == b);
      if (bk[c] == b) pos = (int)(base[b] + off[b] + (uint32_t)__popcll(mb & ltm));
      off[b] += (uint32_t)__popcll(mb);
    }
    snidx[(size_t)a * NEG_ + pos] = e[c];
  }
}

// ---------------- K6a: negatives — UNCHANGED from R9 (proven 258 us @ 87% VALU) ----------------
__global__ __launch_bounds__(64) void k_neg(const uint32_t* __restrict__ pair8,
    const int* __restrict__ snidx, const int* __restrict__ boff,
    const int* __restrict__ aidx, float2* __restrict__ partial) {
  __shared__ float4 anc[260];    // two regions: [0..128), [130..258) — bank-staggered
  int bid = blockIdx.x;
  int bucket = bid & 7;          // XCD-affine
  int pr = bid >> 3;
  int a0 = pr * 2, a1 = a0 + 1;
  int lane = threadIdx.x;

  int ap0 = aidx[a0], ap1 = aidx[a1];
  uint2 d0 = ((const uint2*)(pair8 + (size_t)ap0 * 128))[lane];
  uint2 d1 = ((const uint2*)(pair8 + (size_t)ap1 * 128))[lane];
  {
    v2f ex = cvt8<0>(d0.x), ey = cvt8<1>(d0.x), ez = cvt8<0>(d0.y), ew = cvt8<1>(d0.y);
    anc[lane * 2]     = make_float4(ex.x, ex.y, ey.x, ey.y);
    anc[lane * 2 + 1] = make_float4(ez.x, ez.y, ew.x, ew.y);
    ex = cvt8<0>(d1.x); ey = cvt8<1>(d1.x); ez = cvt8<0>(d1.y); ew = cvt8<1>(d1.y);
    anc[130 + lane * 2]     = make_float4(ex.x, ex.y, ey.x, ey.y);
    anc[130 + lane * 2 + 1] = make_float4(ez.x, ez.y, ew.x, ew.y);
  }
  __syncthreads();

  int s0 = boff[a0 * 9 + bucket], e0i = boff[a0 * 9 + bucket + 1];
  int s1 = boff[a1 * 9 + bucket], e1i = boff[a1 * 9 + bucket + 1];
  int L0 = e0i - s0, L1 = e1i - s1, Lt = L0 + L1;
  const int* list0 = snidx + (size_t)a0 * NEG_ + s0;
  const int* list1 = snidx + (size_t)a1 * NEG_ + s1;

  float m0 = -1e30f, l0 = 0.f, m1 = -1e30f, l1 = 0.f;

  for (int r = 0; r * 64 < Lt; ++r) {
    int g = r * 64 + lane;
    bool act = g < Lt;
    int which = (act && g >= L0) ? 1 : 0;
    int j = which ? (g - L0) : g;
    int p = act ? (which ? list1[j] : list0[j]) : ap0;
    const uint4* rp = (const uint4*)(pair8 + (size_t)p * 128);
    const float4* A = anc + which * 130;
    float sT = 0.f, sL = 0.f;
    uint4 c0 = rp[0], c1 = rp[1];
#pragma unroll 1
    for (int it = 0; it < 16; ++it) {
      int nx = ((it + 1) & 15) * 2;
      uint4 n0 = rp[nx], n1 = rp[nx + 1];
      uint32_t dws[8] = {c0.x, c0.y, c0.z, c0.w, c1.x, c1.y, c1.z, c1.w};
      float pp = 1.0f, pq = 1.0f;
#pragma unroll
      for (int gq = 0; gq < 4; ++gq) {
        float4 acA = A[it * 8 + gq * 2];
        float4 acB = A[it * 8 + gq * 2 + 1];
        v2f e0v = cvt8<0>(dws[2 * gq]),     e1v = cvt8<1>(dws[2 * gq]);
        v2f e2v = cvt8<0>(dws[2 * gq + 1]), e3v = cvt8<1>(dws[2 * gq + 1]);
        float dn0 = acA.y + e0v.y, dn1 = acA.w + e1v.y;
        float dn2 = acB.y + e2v.y, dn3 = acB.w + e3v.y;
        float d01 = dn0 * dn1, d23 = dn2 * dn3;
        float R01 = fastrcp(d01), R23 = fastrcp(d23);
        pp *= d01; pq *= d23;
        float r0 = dn1 * R01, r1 = dn0 * R01, r2 = dn3 * R23, r3 = dn2 * R23;
        float f0 = acA.x - e0v.x, f1 = acA.z - e1v.x;
        float f2 = acB.x - e2v.x, f3 = acB.z - e3v.x;
        sT = fmaf(f0 * f0, r0, sT); sT = fmaf(f1 * f1, r1, sT);
        sT = fmaf(f2 * f2, r2, sT); sT = fmaf(f3 * f3, r3, sT);
      }
      sL += __logf(pp * pq);   // 16-ch product, range [0.2^16, 2^16] — safe
      c0 = n0; c1 = n1;
    }
    float lg = -(sT + sL) * (1.0f / 256.0f);
    if (act) { if (which) lse_up(lg, m1, l1); else lse_up(lg, m0, l0); }
  }
#pragma unroll
  for (int o = 32; o > 0; o >>= 1) {
    float mo = __shfl_xor(m0, o, 64), lo = __shfl_xor(l0, o, 64);
    lse_merge(m0, l0, mo, lo);
    mo = __shfl_xor(m1, o, 64); lo = __shfl_xor(l1, o, 64);
    lse_merge(m1, l1, mo, lo);
  }
  if (lane == 0) {
    partial[a0 * NBUCK + bucket] = make_float2(m0, l0);
    partial[a1 * NBUCK + bucket] = make_float2(m1, l1);
  }
}

// ---------------- K6b: pos + gens + merge partials ----------------
__global__ __launch_bounds__(256, 4) void k_fin(const uint32_t* __restrict__ pair8,
    const float* __restrict__ phat, const float* __restrict__ psig,
    const float* __restrict__ ghat, const int* __restrict__ aidx,
    const float2* __restrict__ partial, float* __restrict__ out) {
  __shared__ float2 ancG[C_];   // {w, ahat*w}
  __shared__ float redm[3][4];
  __shared__ float2 mlw[4];

  int bid = blockIdx.x;
  int i = bid >> 8;
  int t = threadIdx.x, w = t >> 6, lane = t & 63;

  int ap = aidx[bid];
  uint32_t ad = pair8[(size_t)ap * 128 + (t >> 1)];
  v2f ae0 = cvt8<0>(ad), ae1 = cvt8<1>(ad);
  float ahat = (t & 1) ? ae1.x : ae0.x;
  float asg = (t & 1) ? ae1.y : ae0.y;
  float wv = fastrcp(asg);
  ancG[t] = make_float2(wv, ahat * wv);

  float pm = phat[i * C_ + t];
  float ps = psig[i * C_ + t];
  float dnp = asg + ps;
  float dd = ahat - pm;
  float post = fmaf(dd * dd, fastrcp(dnp), __logf(dnp));
  float a1t = ahat * ahat * wv;
  float lat = __logf(asg);
  wred3(post, a1t, lat);
  if (lane == 0) { redm[0][w] = post; redm[1][w] = a1t; redm[2][w] = lat; }
  __syncthreads();
  float postS = redm[0][0] + redm[0][1] + redm[0][2] + redm[0][3];
  float Kc = (redm[1][0] + redm[1][1] + redm[1][2] + redm[1][3])
           + (redm[2][0] + redm[2][1] + redm[2][2] + redm[2][3]);
  float logit0 = -postS * (1.0f / 256.0f);

  float m = -1e30f, l = 0.0f;
  const float4* ancGf = (const float4*)ancG;
  if (lane < 36) {
    int g = lane * 4 + w;
    const float4* gp = (const float4*)(ghat + ((size_t)(i * GENV_ + g)) * C_);
    float a1 = 0.f, a2 = 0.f;
    for (int itr = 0; itr < 64; ++itr) {
      float4 gv = gp[itr];
      float4 g01 = ancGf[itr * 2];
      float4 g23 = ancGf[itr * 2 + 1];
      a1 = fmaf(gv.x * gv.x, g01.x, a1); a2 = fmaf(gv.x, g01.y, a2);
      a1 = fmaf(gv.y * gv.y, g01.z, a1); a2 = fmaf(gv.y, g01.w, a2);
      a1 = fmaf(gv.z * gv.z, g23.x, a1); a2 = fmaf(gv.z, g23.y, a2);
      a1 = fmaf(gv.w * gv.w, g23.z, a1); a2 = fmaf(gv.w, g23.w, a2);
    }
    float lg = -(Kc + a1 - 2.0f * a2) * (1.0f / 256.0f);
    lse_up(lg, m, l);
  }
#pragma unroll
  for (int o = 32; o > 0; o >>= 1) {
    float mo = __shfl_xor(m, o, 64);
    float lo = __shfl_xor(l, o, 64);
    lse_merge(m, l, mo, lo);
  }
  if (lane == 0) mlw[w] = make_float2(m, l);
  __syncthreads();
  if (t == 0) {
    float mm = mlw[0].x, ll = mlw[0].y;
    lse_merge(mm, ll, mlw[1].x, mlw[1].y);
    lse_merge(mm, ll, mlw[2].x, mlw[2].y);
    lse_merge(mm, ll, mlw[3].x, mlw[3].y);
    const float2* pp = partial + (size_t)bid * NBUCK;
#pragma unroll
    for (int b = 0; b < NBUCK; ++b) lse_merge(mm, ll, pp[b].x, pp[b].y);
    lse_merge(mm, ll, logit0, 1.0f);
    float lse = mm + __logf(ll);
    float contrib = logit0 - lse;
    atomicAdd(out, -contrib * (1.0f / (19.0f * 256.0f)));
  }
}

// ---------------- host ----------------
extern "C" void kernel_launch(void* const* d_in, const int* in_sizes, int n_in,
                              void* d_out, int out_size, void* d_ws, size_t ws_size,
                              hipStream_t stream) {
  const float* mu    = (const float*)d_in[0];
  const float* sg    = (const float*)d_in[1];
  const float* label = (const float*)d_in[2];
  const float* mask  = (const float*)d_in[3];
  const float* prob  = (const float*)d_in[4];
  const float* mmu   = (const float*)d_in[5];
  const float* msg   = (const float*)d_in[6];

  char* ws = (char*)d_ws;
  size_t off = 0;
  auto take = [&](size_t bytes) { size_t r = off; off = (off + bytes + 255) & ~(size_t)255; return r; };
  size_t o_pair8 = take((size_t)P_ * 128 * 4);   // 32 MB
  size_t o_rnrm  = take((size_t)P_ * 8);
  size_t o_cls   = take((size_t)P_ * 4);
  size_t o_hrd   = take((size_t)P_ * 4);
  size_t o_bcv   = take(S_ * 256 * 4);
  size_t o_bch   = take(S_ * 256 * 4);
  size_t o_bov   = take(S_ * 256 * 4);
  size_t o_boh   = take(S_ * 256 * 4);
  size_t o_cntv  = take(S_ * 4);
  size_t o_cnth  = take(S_ * 4);
  size_t o_basev = take(S_ * 4);
  size_t o_baseh = take(S_ * 4);
  size_t o_posv  = take((size_t)P_ * 4);
  size_t o_posh  = take((size_t)P_ * 4);
  size_t o_part  = take((size_t)256 * 2 * S_ * C_ * 4);
  size_t o_pmu   = take(S_ * C_ * 4);
  size_t o_psig  = take(S_ * C_ * 4);
  size_t o_phat  = take(S_ * C_ * 4);
  size_t o_logp  = take(S_ * 18 * 4);
  size_t o_keys  = take(S_ * 8 * 4);
  size_t o_aidx  = take(S_ * Q_ * 4);
  size_t o_nidx  = take((size_t)S_ * NS_ * 4);
  size_t o_snidx = take((size_t)S_ * NS_ * 4);
  size_t o_boff  = take((size_t)NANCH * 9 * 4);
  size_t o_lpar  = take((size_t)NANCH * NBUCK * 8);
  size_t o_ghat  = take((size_t)S_ * GENV_ * C_ * 4);
  if (ws_size < off) return;

  uint32_t* pair8 = (uint32_t*)(ws + o_pair8);
  float2*   rnrm  = (float2*)(ws + o_rnrm);
  int*      cls   = (int*)(ws + o_cls);
  int*      hrd   = (int*)(ws + o_hrd);
  int*      bcv   = (int*)(ws + o_bcv);
  int*      bch   = (int*)(ws + o_bch);
  int*      bov   = (int*)(ws + o_bov);
  int*      boh   = (int*)(ws + o_boh);
  int*      cntv  = (int*)(ws + o_cntv);
  int*      cnth  = (int*)(ws + o_cnth);
  int*      basev = (int*)(ws + o_basev);
  int*      baseh = (int*)(ws + o_baseh);
  int*      posv  = (int*)(ws + o_posv);
  int*      posh  = (int*)(ws + o_posh);
  float*    part  = (float*)(ws + o_part);
  float*    pmu   = (float*)(ws + o_pmu);
  float*    psig  = (float*)(ws + o_psig);
  float*    phat  = (float*)(ws + o_phat);
  float*    logp  = (float*)(ws + o_logp);
  uint32_t* keys  = (uint32_t*)(ws + o_keys);
  int*      aidx  = (int*)(ws + o_aidx);
  int*      nidx  = (int*)(ws + o_nidx);
  int*      snidx = (int*)(ws + o_snidx);
  int*      boff  = (int*)(ws + o_boff);
  float2*   lpar  = (float2*)(ws + o_lpar);
  float*    ghat  = (float*)(ws + o_ghat);

  hipMemsetAsync(d_out, 0, (size_t)out_size * 4, stream);

  k_classify<<<256, 256, 0, stream>>>(label, mask, prob, mu, keys, cls, hrd, bcv, bch, rnrm);
  k_pack<<<dim3(P_ / 64, C_ / 64), 256, 0, stream>>>(mu, sg, rnrm, pair8);
  k_scan<<<1, 320, 0, stream>>>(bcv, bch, bov, boh, cntv, cnth, basev, baseh);
  k_fillsums<<<256, 256, 0, stream>>>(pair8, rnrm, cls, hrd, bov, boh, basev, baseh, posv, posh, part);
  k_proto<<<S_, 1024, 0, stream>>>(part, mmu, msg, pmu, psig, phat);
  k_simlogp<<<S_, 64, 0, stream>>>(phat, psig, logp);
  k_gensample<<<GENV_ * S_ + 512 * S_, 256, 0, stream>>>(keys, pmu, psig, logp, cntv, basev, posv, ghat, nidx);
  k_bucket<<<NANCH, 64, 0, stream>>>(keys, cnth, baseh, posh, nidx, snidx, boff, aidx);
  k_neg<<<NBUCK * NPAIR, 64, 0, stream>>>(pair8, snidx, boff, aidx, lpar);
  k_fin<<<NANCH, 256, 0, stream>>>(pair8, phat, psig, ghat, aidx, lpar, (float*)d_out);
}

// Round 11
// 586.662 us; speedup vs baseline: 1.3244x; 1.0298x over previous
//
#include <hip/hip_runtime.h>
#include <hip/hip_fp16.h>
#include <hip/hip_fp8.h>
#include <cstdint>

#define B_   4
#define S_   19
#define HW_  16384
#define P_   65536
#define C_   256
#define Q_   256
#define NEG_ 512
#define NS_  131072
#define GENV_ 144
#define NANCH (S_ * 256)     // 4864
#define NBUCK 8

typedef float v2f __attribute__((ext_vector_type(2)));

#if __has_builtin(__builtin_amdgcn_cvt_pk_f32_fp8) && __has_builtin(__builtin_amdgcn_cvt_pk_fp8_f32)
#define HAVE_HW_FP8 1
#endif

template<int W> __device__ __forceinline__ v2f cvt8(uint32_t d) {
#ifdef HAVE_HW_FP8
  v2f r = __builtin_amdgcn_cvt_pk_f32_fp8((int)d, W);
  return r;
#else
  __hip_fp8_e4m3 h0, h1;
  h0.__x = (uint8_t)(d >> (W * 16));
  h1.__x = (uint8_t)(d >> (W * 16 + 8));
  v2f r; r.x = (float)h0; r.y = (float)h1; return r;
#endif
}
template<int W> __device__ __forceinline__ uint32_t pk8(float a, float b, uint32_t old) {
#ifdef HAVE_HW_FP8
  return (uint32_t)__builtin_amdgcn_cvt_pk_fp8_f32(a, b, (int)old, W);
#else
  __hip_fp8_e4m3 ha(a), hb(b);
  uint32_t v = (uint32_t)ha.__x | ((uint32_t)hb.__x << 8);
  return (old & (W ? 0x0000FFFFu : 0xFFFF0000u)) | (v << (W * 16));
#endif
}

// ---------------- threefry2x32 (JAX-exact) ----------------
__device__ __forceinline__ void tf2x32(uint32_t k0, uint32_t k1, uint32_t x0, uint32_t x1,
                                       uint32_t& o0, uint32_t& o1) {
  uint32_t k2 = k0 ^ k1 ^ 0x1BD11BDAu;
#define TFR(r) { x0 += x1; x1 = (x1 << r) | (x1 >> (32 - r)); x1 ^= x0; }
  x0 += k0; x1 += k1;
  TFR(13) TFR(15) TFR(26) TFR(6)  x0 += k1; x1 += k2 + 1u;
  TFR(17) TFR(29) TFR(16) TFR(24) x0 += k2; x1 += k0 + 2u;
  TFR(13) TFR(15) TFR(26) TFR(6)  x0 += k0; x1 += k1 + 3u;
  TFR(17) TFR(29) TFR(16) TFR(24) x0 += k1; x1 += k2 + 4u;
  TFR(13) TFR(15) TFR(26) TFR(6)  x0 += k2; x1 += k0 + 5u;
#undef TFR
  o0 = x0; o1 = x1;
}

__device__ __forceinline__ uint32_t rbits(uint32_t k0, uint32_t k1, uint32_t n) {
  uint32_t a, b; tf2x32(k0, k1, 0u, n, a, b); return a ^ b;
}

__device__ __forceinline__ float bits2f01(uint32_t b) {
  return __uint_as_float((b >> 9) | 0x3f800000u) - 1.0f;
}

__device__ __forceinline__ float fastrcp(float x) {
  float r; asm("v_rcp_f32 %0, %1" : "=v"(r) : "v"(x)); return r;
}

__device__ __forceinline__ float wred(float v) {
#pragma unroll
  for (int off = 32; off > 0; off >>= 1) v += __shfl_xor(v, off, 64);
  return v;
}
__device__ __forceinline__ void wred3(float& a, float& b, float& c) {
#pragma unroll
  for (int off = 32; off > 0; off >>= 1) {
    a += __shfl_xor(a, off, 64);
    b += __shfl_xor(b, off, 64);
    c += __shfl_xor(c, off, 64);
  }
}

__device__ __forceinline__ void lse_up(float lg, float& m, float& l) {
  if (lg > m) { l = l * __expf(m - lg) + 1.0f; m = lg; }
  else l += __expf(lg - m);
}
__device__ __forceinline__ void lse_merge(float& m, float& l, float mo, float lo) {
  float mn = fmaxf(m, mo);
  l = l * __expf(m - mn) + lo * __expf(mo - mn);
  m = mn;
}

// XLA ErfInv32 (Giles)
__device__ __forceinline__ float erfinv_f(float x) {
  float w = -__logf(fmaxf(fmaf(-x, x, 1.0f), 1e-37f));
  float p;
  if (w < 5.0f) {
    w -= 2.5f;
    p = 2.81022636e-08f;
    p = fmaf(p, w, 3.43273939e-07f);
    p = fmaf(p, w, -3.5233877e-06f);
    p = fmaf(p, w, -4.39150654e-06f);
    p = fmaf(p, w, 0.00021858087f);
    p = fmaf(p, w, -0.00125372503f);
    p = fmaf(p, w, -0.00417768164f);
    p = fmaf(p, w, 0.246640727f);
    p = fmaf(p, w, 1.50140941f);
  } else {
    w = sqrtf(w) - 3.0f;
    p = -0.000200214257f;
    p = fmaf(p, w, 0.000100950558f);
    p = fmaf(p, w, 0.00134934322f);
    p = fmaf(p, w, -0.00367342844f);
    p = fmaf(p, w, 0.00573950773f);
    p = fmaf(p, w, -0.0076224613f);
    p = fmaf(p, w, 0.00943887047f);
    p = fmaf(p, w, 1.00167406f);
    p = fmaf(p, w, 2.83297682f);
  }
  return p * x;
}

// ---------------- K1: keys (block 0) + class/hard + per-block counts + mu norm ----------------
__global__ __launch_bounds__(256) void k_classify(const float* __restrict__ label,
    const float* __restrict__ mask, const float* __restrict__ prob,
    const float* __restrict__ mu,
    uint32_t* __restrict__ keys, int* __restrict__ cls, int* __restrict__ hrd,
    int* __restrict__ bcv, int* __restrict__ bch, float2* __restrict__ rnrm) {
  __shared__ int hv[S_], hh[S_];
  int t = threadIdx.x;
  if (t < S_) { hv[t] = 0; hh[t] = 0; }
  if (blockIdx.x == 0 && t < S_) {
    uint32_t f0, f1;
    tf2x32(0u, 1234u, 0u, (uint32_t)t, f0, f1);
#pragma unroll
    for (int k = 0; k < 4; ++k) {
      uint32_t a, b;
      tf2x32(f0, f1, 0u, (uint32_t)k, a, b);
      keys[t * 8 + k * 2] = a; keys[t * 8 + k * 2 + 1] = b;
    }
  }
  __syncthreads();
  int p = blockIdx.x * 256 + t;
  int b = p >> 14, rem = p & (HW_ - 1);
  int sp = -1;
#pragma unroll
  for (int s = 0; s < S_; ++s) {
    float l = label[((b * S_ + s) << 14) + rem];
    if (l > 0.5f) sp = s;
  }
  if (mask[(b << 14) + rem] <= 0.5f) sp = -1;
  int h = 0;
  if (sp >= 0) h = (prob[((b * S_ + sp) << 14) + rem] < 0.97f) ? 1 : 0;
  cls[p] = sp; hrd[p] = h;
  if (sp >= 0) { atomicAdd(&hv[sp], 1); if (h) atomicAdd(&hh[sp], 1); }
  __syncthreads();
  if (t < S_) { bcv[t * 256 + blockIdx.x] = hv[t]; bch[t * 256 + blockIdx.x] = hh[t]; }
  // ---- fused: per-pixel mu norm (exact f32) ----
  const float* basep = mu + (((size_t)(b * C_)) << 14) + rem;
  float s2 = 0.f;
#pragma unroll 8
  for (int c = 0; c < C_; ++c) {
    float v = basep[(size_t)c << 14];
    s2 = fmaf(v, v, s2);
  }
  float nrm = sqrtf(s2);
  rnrm[p] = make_float2(fastrcp(fmaxf(nrm, 1e-12f)), nrm);
}

// ---------------- K1b: pack (B,C,H,W) f32 -> (P,C) fp8 {muhat, sg} interleaved ----------------
__global__ __launch_bounds__(256) void k_pack(const float* __restrict__ mu,
    const float* __restrict__ sg, const float2* __restrict__ rnrm,
    uint32_t* __restrict__ pair8) {
  __shared__ float smu[64][65];
  __shared__ float ssg[64][65];
  __shared__ float srn[64];
  int p0 = blockIdx.x * 64, c0 = blockIdx.y * 64;
  int b = p0 >> 14, rem0 = p0 & (HW_ - 1);
  if (threadIdx.x < 64) srn[threadIdx.x] = rnrm[p0 + threadIdx.x].x;
  int px = threadIdx.x & 63, cy = threadIdx.x >> 6;
#pragma unroll
  for (int itr = 0; itr < 16; ++itr) {
    int cl = cy + itr * 4;
    int addr = ((b * C_ + c0 + cl) << 14) + rem0 + px;
    smu[cl][px] = mu[addr];
    ssg[cl][px] = sg[addr];
  }
  __syncthreads();
#pragma unroll
  for (int itr = 0; itr < 8; ++itr) {
    int e = itr * 256 + threadIdx.x;
    int pxl = e >> 5, dw = e & 31, cl = dw * 2;
    float rn = srn[pxl];
    uint32_t wd = pk8<0>(smu[cl][pxl] * rn, ssg[cl][pxl], 0u);
    wd = pk8<1>(smu[cl + 1][pxl] * rn, ssg[cl + 1][pxl], wd);
    pair8[(size_t)(p0 + pxl) * 128 + (c0 >> 1) + dw] = wd;
  }
}

// parallel two-level scan: 304 workers of 16-entry chunks
__global__ __launch_bounds__(320) void k_scan(const int* __restrict__ bcv, const int* __restrict__ bch,
    int* __restrict__ bov, int* __restrict__ boh,
    int* __restrict__ cntv, int* __restrict__ cnth,
    int* __restrict__ basev, int* __restrict__ baseh) {
  __shared__ int psv[S_][16], psh[S_][16], scv[S_], sch[S_];
  int t = threadIdx.x;
  int s = t >> 4, c = t & 15;
  if (t < 304) {
    int sv = 0, sh = 0;
#pragma unroll 4
    for (int b = 0; b < 16; ++b) {
      sv += bcv[s * 256 + c * 16 + b];
      sh += bch[s * 256 + c * 16 + b];
    }
    psv[s][c] = sv; psh[s][c] = sh;
  }
  __syncthreads();
  if (t < S_) {
    int rv = 0, rh = 0;
#pragma unroll
    for (int cc = 0; cc < 16; ++cc) {
      int tv = psv[t][cc]; psv[t][cc] = rv; rv += tv;
      int th = psh[t][cc]; psh[t][cc] = rh; rh += th;
    }
    cntv[t] = rv; cnth[t] = rh; scv[t] = rv; sch[t] = rh;
  }
  __syncthreads();
  if (t == 0) {
    int bv = 0, bh = 0;
    for (int k = 0; k < S_; ++k) { basev[k] = bv; bv += scv[k]; baseh[k] = bh; bh += sch[k]; }
  }
  if (t < 304) {
    int rv = psv[s][c], rh = psh[s][c];
#pragma unroll 4
    for (int b = 0; b < 16; ++b) {
      int i0 = s * 256 + c * 16 + b;
      int tv = bcv[i0]; bov[i0] = rv; rv += tv;
      int th = bch[i0]; boh[i0] = rh; rh += th;
    }
  }
}

// ---------------- K2: fused fill (ballot-ranked pos lists) + per-class partial sums ----------------
__global__ __launch_bounds__(256) void k_fillsums(const uint32_t* __restrict__ pair8,
    const float2* __restrict__ rnrm, const int* __restrict__ cls, const int* __restrict__ hrd,
    const int* __restrict__ bov, const int* __restrict__ boh,
    const int* __restrict__ basev, const int* __restrict__ baseh,
    int* __restrict__ posv, int* __restrict__ posh, float* __restrict__ part) {
  __shared__ float lacc[S_][2][C_];   // 38 KB
  __shared__ int scls[256];
  __shared__ float snrm[256];
  __shared__ int cntW[4][S_], cnthW[4][S_];
  int t = threadIdx.x;
  int w = t >> 6, lane = t & 63;
  int p0 = blockIdx.x * 256;
  int p = p0 + t;
  int s = cls[p]; int h = hrd[p];
  scls[t] = s;
  snrm[t] = rnrm[p].y;
  for (int e = t; e < S_ * 2 * C_; e += 256) (&lacc[0][0][0])[e] = 0.f;
  // ---- ballot-based stable rank (register-only, no LDS dependency) ----
  unsigned long long ltm = (1ull << lane) - 1ull;
  unsigned long long mv = 0ull, mh = 0ull;
  for (int sc = 0; sc < S_; ++sc) {
    unsigned long long mb = __ballot(s == sc);
    unsigned long long mbh = __ballot(s == sc && h);
    if (s == sc) { mv = mb; mh = mbh; }
    if (lane == 0) { cntW[w][sc] = (int)__popcll(mb); cnthW[w][sc] = (int)__popcll(mbh); }
  }
  __syncthreads();
  if (s >= 0) {
    int rv = (int)__popcll(mv & ltm);
    int rh = (int)__popcll(mh & ltm);
    for (int w2 = 0; w2 < w; ++w2) { rv += cntW[w2][s]; rh += cnthW[w2][s]; }
    posv[basev[s] + bov[s * 256 + blockIdx.x] + rv] = p;
    if (h) posh[baseh[s] + boh[s * 256 + blockIdx.x] + rh] = p;
  }
  // ---- sums: thread owns channel t (column of lacc) ----
  int half = t & 1, dwi = t >> 1;
  uint32_t d = pair8[(size_t)p0 * 128 + dwi];
  for (int pp = 0; pp < 256; ++pp) {
    uint32_t dnx = (pp + 1 < 256) ? pair8[(size_t)(p0 + pp + 1) * 128 + dwi] : 0u;
    int sc = scls[pp];
    if (sc >= 0) {
      v2f e = half ? cvt8<1>(d) : cvt8<0>(d);
      float ia = fastrcp(e.y);
      lacc[sc][0][t] += ia;
      lacc[sc][1][t] += ia * e.x * snrm[pp];
    }
    d = dnx;
  }
  __syncthreads();
  float* dst = part + (size_t)blockIdx.x * (2 * S_ * C_);
  for (int e = t; e < S_ * 2 * C_; e += 256) dst[e] = (&lacc[0][0][0])[e];
}

// ---------------- K4: prototypes — 1024 threads, 4-way reduction over part blocks ----------------
__global__ __launch_bounds__(1024) void k_proto(const float* __restrict__ part,
    const float* __restrict__ mmu, const float* __restrict__ msg,
    float* __restrict__ pmu, float* __restrict__ psig, float* __restrict__ phat) {
  __shared__ float redA[4][C_];
  __shared__ float redB[4][C_];
  __shared__ float red[4];
  int s = blockIdx.x;
  int t = threadIdx.x;
  int c = t & 255, grp = t >> 8;
  float A = 0.f, Bv = 0.f;
  for (int b = grp * 64; b < grp * 64 + 64; ++b) {
    const float* pb = part + (size_t)b * (2 * S_ * C_) + (s * 2) * C_;
    A += pb[c];
    Bv += pb[C_ + c];
  }
  redA[grp][c] = A; redB[grp][c] = Bv;
  __syncthreads();
  float pm = 0.f;
  if (grp == 0) {
    A = redA[0][c] + redA[1][c] + redA[2][c] + redA[3][c];
    Bv = redB[0][c] + redB[1][c] + redB[2][c] + redB[3][c];
    int e = s * C_ + c;
    float psb = 1.0f / A;
    float pmb = psb * Bv;
    float ms = msg[e], mm = mmu[e];
    float ps = 1.0f / (1.0f / psb + 1.0f / ms);
    pm = ps * (mm / ms + pmb / psb);
    pmu[e] = pm; psig[e] = ps;
    float w = wred(pm * pm);
    int lane = c & 63, wv = c >> 6;
    if (lane == 0) red[wv] = w;
  }
  __syncthreads();
  if (grp == 0) {
    float tot = red[0] + red[1] + red[2] + red[3];
    float nrm = fmaxf(sqrtf(tot), 1e-12f);
    phat[s * C_ + c] = pm / nrm;
  }
}

// ---------------- K5a: sim -> log_softmax ----------------
__global__ __launch_bounds__(64) void k_simlogp(const float* __restrict__ phat,
    const float* __restrict__ psig, float* __restrict__ logp) {
  int i = blockIdx.x, lane = threadIdx.x;
  int c0 = lane * 4;
  float phi[4], psi[4];
#pragma unroll
  for (int k = 0; k < 4; ++k) { phi[k] = phat[i * C_ + c0 + k]; psi[k] = psig[i * C_ + c0 + k]; }
  float xs[18];
#pragma unroll
  for (int j = 0; j < 18; ++j) {
    int o = i + 1 + j; if (o >= S_) o -= S_;
    float t = 0.f;
#pragma unroll
    for (int k = 0; k < 4; ++k) {
      float d = phi[k] - phat[o * C_ + c0 + k];
      float dn = psi[k] + psig[o * C_ + c0 + k];
      t += d * d / dn + logf(dn);
    }
    t = wred(t);
    xs[j] = (-0.5f * t * (1.0f / 256.0f)) * 2.0f;
  }
  float m = xs[0];
#pragma unroll
  for (int j = 1; j < 18; ++j) m = fmaxf(m, xs[j]);
  float se = 0.f;
#pragma unroll
  for (int j = 0; j < 18; ++j) se += expf(xs[j] - m);
  float lg = logf(se);
  if (lane == 0) {
#pragma unroll
    for (int j = 0; j < 18; ++j) logp[i * 18 + j] = xs[j] - m - lg;
  }
}

// ---------------- K5bc: fused generalized prototypes + class/negative sampling ----------------
__global__ __launch_bounds__(256) void k_gensample(const uint32_t* __restrict__ keys,
    const float* __restrict__ pmu, const float* __restrict__ psig,
    const float* __restrict__ logp, const int* __restrict__ cntv, const int* __restrict__ basev,
    const int* __restrict__ posv, float* __restrict__ ghat, int* __restrict__ nidx) {
  __shared__ float red[4];
  __shared__ float elp[18];
  __shared__ int lcnt[S_], lbase[S_];
  int bid = blockIdx.x;
  int t = threadIdx.x;
  if (bid < GENV_ * S_) {
    // ---- gen ----
    int v = bid % GENV_, i = bid / GENV_;
    int c = t;
    int o = i + 1 + (v >> 3); if (o >= S_) o -= S_;
    uint32_t k0 = keys[i * 8 + 6], k1 = keys[i * 8 + 7];
    uint32_t bits = rbits(k0, k1, (uint32_t)(v * C_ + c));
    float f01 = bits2f01(bits);
    const float lo = -0.99999994f;
    float u = fmaxf(f01 * 2.0f + lo, lo);
    float eps = 1.41421356237f * erfinv_f(u);
    float g = pmu[o * C_ + c] + sqrtf(psig[o * C_ + c]) * eps;
    float w = wred(g * g);
    int lane = c & 63, wv = c >> 6;
    if (lane == 0) red[wv] = w;
    __syncthreads();
    float tot = red[0] + red[1] + red[2] + red[3];
    float nrm = fmaxf(sqrtf(tot), 1e-12f);
    ghat[((size_t)(i * GENV_ + v)) * C_ + c] = g / nrm;
  } else {
    // ---- sample ----
    int sid = bid - GENV_ * S_;
    int i = sid / 512;
    int m = (sid % 512) * 256 + t;
    if (t < 18) elp[t] = __expf(-logp[i * 18 + t]);
    if (t < S_) { lcnt[t] = cntv[t]; lbase[t] = basev[t]; }
    __syncthreads();
    uint32_t kc0 = keys[i * 8 + 2], kc1 = keys[i * 8 + 3];
    uint32_t kn0 = keys[i * 8 + 4], kn1 = keys[i * 8 + 5];
    // argmax_s( -log(-log u_s) + lp_s ) == argmin_s( (-log u_s) * exp(-lp_s) )
    float bv = 1e30f; int best = 0;
    for (int s = 0; s < 18; ++s) {
      uint32_t b = rbits(kc0, kc1, (uint32_t)m * 18u + (uint32_t)s);
      float u = fmaxf(bits2f01(b), 1.17549435e-38f);
      float val = (-__logf(u)) * elp[s];
      if (val < bv) { bv = val; best = s; }
    }
    float un = bits2f01(rbits(kn0, kn1, (uint32_t)m));
    int cc = i + 1 + best; if (cc >= S_) cc -= S_;
    int cnt = lcnt[cc];
    int idx = P_ - 1;
    if (cnt > 0) {
      int kk = (int)(un * (float)cnt);
      if (kk >= cnt) kk = cnt - 1;
      idx = posv[lbase[cc] + kk];
    }
    nidx[(size_t)i * NS_ + m] = idx;
  }
}

// ---------------- K5e: bucket sort of negatives + anchor index (fused) ----------------
__global__ __launch_bounds__(64) void k_bucket(const uint32_t* __restrict__ keys,
    const int* __restrict__ cnth, const int* __restrict__ baseh, const int* __restrict__ posh,
    const int* __restrict__ nidx, int* __restrict__ snidx, int* __restrict__ boff,
    int* __restrict__ aidx) {
  int a = blockIdx.x;
  int lane = threadIdx.x;
  if (lane == 0) {
    int i = a >> 8, q = a & 255;
    uint32_t k0 = keys[i * 8 + 0], k1 = keys[i * 8 + 1];
    float u = bits2f01(rbits(k0, k1, (uint32_t)q));
    int cnt = cnth[i];
    int idx = P_ - 1;
    if (cnt > 0) {
      int kk = (int)(u * (float)cnt);
      if (kk >= cnt) kk = cnt - 1;
      idx = posh[baseh[i] + kk];
    }
    aidx[a] = idx;
  }
  const int* src = nidx + (size_t)a * NEG_;
  int e[8], bk[8];
#pragma unroll
  for (int c = 0; c < 8; ++c) { e[c] = src[c * 64 + lane]; bk[c] = (e[c] >> 13) & 7; }
  uint32_t cnt[NBUCK];
#pragma unroll
  for (int b = 0; b < NBUCK; ++b) cnt[b] = 0;
#pragma unroll
  for (int c = 0; c < 8; ++c)
#pragma unroll
    for (int b = 0; b < NBUCK; ++b) {
      unsigned long long mb = __ballot(bk[c] == b);
      cnt[b] += (uint32_t)__popcll(mb);
    }
  uint32_t base[NBUCK]; uint32_t run = 0;
#pragma unroll
  for (int b = 0; b < NBUCK; ++b) { base[b] = run; run += cnt[b]; }
  if (lane < NBUCK) boff[a * 9 + lane] = (int)base[lane];
  if (lane == 0) boff[a * 9 + 8] = NEG_;
  uint32_t off[NBUCK];
#pragma unroll
  for (int b = 0; b < NBUCK; ++b) off[b] = 0;
  unsigned long long ltm = (1ull << lane) - 1ull;
#pragma unroll
  for (int c = 0; c < 8; ++c) {
    int pos = 0;
#pragma unroll
    for (int b = 0; b < NBUCK; ++b) {
      unsigned long long mb = __ballot(bk[c] == b);
      if (bk[c] == b) pos = (int)(base[b] + off[b] + (uint32_t)__popcll(mb & ltm));
      off[b] += (uint32_t)__popcll(mb);
    }
    snidx[(size_t)a * NEG_ + pos] = e[c];
  }
}

// ---------------- K6a: negatives — 4 anchors/block (tail waste 25%->12.5%), same math ----------------
__global__ __launch_bounds__(64) void k_neg(const uint32_t* __restrict__ pair8,
    const int* __restrict__ snidx, const int* __restrict__ boff,
    const int* __restrict__ aidx, float2* __restrict__ partial) {
  __shared__ float4 anc[4][130];   // 4 regions, 130-stride => banks {0,8,16,24}: conflict-free 4-way
  int bid = blockIdx.x;
  int bucket = bid & 7;            // XCD-affine
  int pr = bid >> 3;               // 0..1215
  int a0 = pr * 4;
  int lane = threadIdx.x;

  int apx = aidx[a0 + 0], apy = aidx[a0 + 1], apz = aidx[a0 + 2], apw = aidx[a0 + 3];
  {
    uint2 d = ((const uint2*)(pair8 + (size_t)apx * 128))[lane];
    v2f ex = cvt8<0>(d.x), ey = cvt8<1>(d.x), ez = cvt8<0>(d.y), ew = cvt8<1>(d.y);
    anc[0][lane * 2]     = make_float4(ex.x, ex.y, ey.x, ey.y);
    anc[0][lane * 2 + 1] = make_float4(ez.x, ez.y, ew.x, ew.y);
    d = ((const uint2*)(pair8 + (size_t)apy * 128))[lane];
    ex = cvt8<0>(d.x); ey = cvt8<1>(d.x); ez = cvt8<0>(d.y); ew = cvt8<1>(d.y);
    anc[1][lane * 2]     = make_float4(ex.x, ex.y, ey.x, ey.y);
    anc[1][lane * 2 + 1] = make_float4(ez.x, ez.y, ew.x, ew.y);
    d = ((const uint2*)(pair8 + (size_t)apz * 128))[lane];
    ex = cvt8<0>(d.x); ey = cvt8<1>(d.x); ez = cvt8<0>(d.y); ew = cvt8<1>(d.y);
    anc[2][lane * 2]     = make_float4(ex.x, ex.y, ey.x, ey.y);
    anc[2][lane * 2 + 1] = make_float4(ez.x, ez.y, ew.x, ew.y);
    d = ((const uint2*)(pair8 + (size_t)apw * 128))[lane];
    ex = cvt8<0>(d.x); ey = cvt8<1>(d.x); ez = cvt8<0>(d.y); ew = cvt8<1>(d.y);
    anc[3][lane * 2]     = make_float4(ex.x, ex.y, ey.x, ey.y);
    anc[3][lane * 2 + 1] = make_float4(ez.x, ez.y, ew.x, ew.y);
  }
  __syncthreads();

  int s0 = boff[(a0 + 0) * 9 + bucket], e0 = boff[(a0 + 0) * 9 + bucket + 1];
  int s1 = boff[(a0 + 1) * 9 + bucket], e1 = boff[(a0 + 1) * 9 + bucket + 1];
  int s2 = boff[(a0 + 2) * 9 + bucket], e2 = boff[(a0 + 2) * 9 + bucket + 1];
  int s3 = boff[(a0 + 3) * 9 + bucket], e3 = boff[(a0 + 3) * 9 + bucket + 1];
  int L0 = e0 - s0, L1 = e1 - s1, L2 = e2 - s2, L3 = e3 - s3;
  int c01 = L0 + L1, c012 = c01 + L2, Lt = c012 + L3;
  const int* lst0 = snidx + (size_t)(a0 + 0) * NEG_ + s0;
  const int* lst1 = snidx + (size_t)(a0 + 1) * NEG_ + s1;
  const int* lst2 = snidx + (size_t)(a0 + 2) * NEG_ + s2;
  const int* lst3 = snidx + (size_t)(a0 + 3) * NEG_ + s3;

  float m0 = -1e30f, l0v = 0.f, m1 = -1e30f, l1v = 0.f;
  float m2 = -1e30f, l2v = 0.f, m3 = -1e30f, l3v = 0.f;

  for (int r = 0; r * 64 < Lt; ++r) {
    int g = r * 64 + lane;
    bool act = g < Lt;
    int which = (g >= L0) + (g >= c01) + (g >= c012);
    if (!act) which = 0;
    int sub = (which == 0) ? 0 : (which == 1) ? L0 : (which == 2) ? c01 : c012;
    int j = g - sub;
    const int* lp = (which == 0) ? lst0 : (which == 1) ? lst1 : (which == 2) ? lst2 : lst3;
    int p = act ? lp[j] : apx;
    const uint4* rp = (const uint4*)(pair8 + (size_t)p * 128);
    const float4* A = anc[which];
    float sT = 0.f, sL = 0.f;
    uint4 c0 = rp[0], c1 = rp[1];
#pragma unroll 1
    for (int it = 0; it < 16; ++it) {
      int nx = ((it + 1) & 15) * 2;
      uint4 n0 = rp[nx], n1 = rp[nx + 1];
      uint32_t dws[8] = {c0.x, c0.y, c0.z, c0.w, c1.x, c1.y, c1.z, c1.w};
      float pp = 1.0f, pq = 1.0f;
#pragma unroll
      for (int gq = 0; gq < 4; ++gq) {
        float4 acA = A[it * 8 + gq * 2];
        float4 acB = A[it * 8 + gq * 2 + 1];
        v2f e0v = cvt8<0>(dws[2 * gq]),     e1v = cvt8<1>(dws[2 * gq]);
        v2f e2v = cvt8<0>(dws[2 * gq + 1]), e3v = cvt8<1>(dws[2 * gq + 1]);
        float dn0 = acA.y + e0v.y, dn1 = acA.w + e1v.y;
        float dn2 = acB.y + e2v.y, dn3 = acB.w + e3v.y;
        float d01 = dn0 * dn1, d23 = dn2 * dn3;
        float R01 = fastrcp(d01), R23 = fastrcp(d23);
        pp *= d01; pq *= d23;
        float r0 = dn1 * R01, r1 = dn0 * R01, r2 = dn3 * R23, r3 = dn2 * R23;
        float f0 = acA.x - e0v.x, f1 = acA.z - e1v.x;
        float f2 = acB.x - e2v.x, f3 = acB.z - e3v.x;
        sT = fmaf(f0 * f0, r0, sT); sT = fmaf(f1 * f1, r1, sT);
        sT = fmaf(f2 * f2, r2, sT); sT = fmaf(f3 * f3, r3, sT);
      }
      sL += __logf(pp * pq);   // 16-ch product, range [0.2^16, 2^16] — safe
      c0 = n0; c1 = n1;
    }
    float lg = -(sT + sL) * (1.0f / 256.0f);
    if (act) {
      if (which == 0) lse_up(lg, m0, l0v);
      else if (which == 1) lse_up(lg, m1, l1v);
      else if (which == 2) lse_up(lg, m2, l2v);
      else lse_up(lg, m3, l3v);
    }
  }
#pragma unroll
  for (int o = 32; o > 0; o >>= 1) {
    float mo, lo;
    mo = __shfl_xor(m0, o, 64); lo = __shfl_xor(l0v, o, 64); lse_merge(m0, l0v, mo, lo);
    mo = __shfl_xor(m1, o, 64); lo = __shfl_xor(l1v, o, 64); lse_merge(m1, l1v, mo, lo);
    mo = __shfl_xor(m2, o, 64); lo = __shfl_xor(l2v, o, 64); lse_merge(m2, l2v, mo, lo);
    mo = __shfl_xor(m3, o, 64); lo = __shfl_xor(l3v, o, 64); lse_merge(m3, l3v, mo, lo);
  }
  if (lane == 0) {
    partial[(a0 + 0) * NBUCK + bucket] = make_float2(m0, l0v);
    partial[(a0 + 1) * NBUCK + bucket] = make_float2(m1, l1v);
    partial[(a0 + 2) * NBUCK + bucket] = make_float2(m2, l2v);
    partial[(a0 + 3) * NBUCK + bucket] = make_float2(m3, l3v);
  }
}

// ---------------- K6b: pos + gens + merge partials ----------------
__global__ __launch_bounds__(256, 4) void k_fin(const uint32_t* __restrict__ pair8,
    const float* __restrict__ phat, const float* __restrict__ psig,
    const float* __restrict__ ghat, const int* __restrict__ aidx,
    const float2* __restrict__ partial, float* __restrict__ out) {
  __shared__ float2 ancG[C_];   // {w, ahat*w}
  __shared__ float redm[3][4];
  __shared__ float2 mlw[4];

  int bid = blockIdx.x;
  int i = bid >> 8;
  int t = threadIdx.x, w = t >> 6, lane = t & 63;

  int ap = aidx[bid];
  uint32_t ad = pair8[(size_t)ap * 128 + (t >> 1)];
  v2f ae0 = cvt8<0>(ad), ae1 = cvt8<1>(ad);
  float ahat = (t & 1) ? ae1.x : ae0.x;
  float asg = (t & 1) ? ae1.y : ae0.y;
  float wv = fastrcp(asg);
  ancG[t] = make_float2(wv, ahat * wv);

  float pm = phat[i * C_ + t];
  float ps = psig[i * C_ + t];
  float dnp = asg + ps;
  float dd = ahat - pm;
  float post = fmaf(dd * dd, fastrcp(dnp), __logf(dnp));
  float a1t = ahat * ahat * wv;
  float lat = __logf(asg);
  wred3(post, a1t, lat);
  if (lane == 0) { redm[0][w] = post; redm[1][w] = a1t; redm[2][w] = lat; }
  __syncthreads();
  float postS = redm[0][0] + redm[0][1] + redm[0][2] + redm[0][3];
  float Kc = (redm[1][0] + redm[1][1] + redm[1][2] + redm[1][3])
           + (redm[2][0] + redm[2][1] + redm[2][2] + redm[2][3]);
  float logit0 = -postS * (1.0f / 256.0f);

  float m = -1e30f, l = 0.0f;
  const float4* ancGf = (const float4*)ancG;
  if (lane < 36) {
    int g = lane * 4 + w;
    const float4* gp = (const float4*)(ghat + ((size_t)(i * GENV_ + g)) * C_);
    float a1 = 0.f, a2 = 0.f;
    for (int itr = 0; itr < 64; ++itr) {
      float4 gv = gp[itr];
      float4 g01 = ancGf[itr * 2];
      float4 g23 = ancGf[itr * 2 + 1];
      a1 = fmaf(gv.x * gv.x, g01.x, a1); a2 = fmaf(gv.x, g01.y, a2);
      a1 = fmaf(gv.y * gv.y, g01.z, a1); a2 = fmaf(gv.y, g01.w, a2);
      a1 = fmaf(gv.z * gv.z, g23.x, a1); a2 = fmaf(gv.z, g23.y, a2);
      a1 = fmaf(gv.w * gv.w, g23.z, a1); a2 = fmaf(gv.w, g23.w, a2);
    }
    float lg = -(Kc + a1 - 2.0f * a2) * (1.0f / 256.0f);
    lse_up(lg, m, l);
  }
#pragma unroll
  for (int o = 32; o > 0; o >>= 1) {
    float mo = __shfl_xor(m, o, 64);
    float lo = __shfl_xor(l, o, 64);
    lse_merge(m, l, mo, lo);
  }
  if (lane == 0) mlw[w] = make_float2(m, l);
  __syncthreads();
  if (t == 0) {
    float mm = mlw[0].x, ll = mlw[0].y;
    lse_merge(mm, ll, mlw[1].x, mlw[1].y);
    lse_merge(mm, ll, mlw[2].x, mlw[2].y);
    lse_merge(mm, ll, mlw[3].x, mlw[3].y);
    const float2* pp = partial + (size_t)bid * NBUCK;
#pragma unroll
    for (int b = 0; b < NBUCK; ++b) lse_merge(mm, ll, pp[b].x, pp[b].y);
    lse_merge(mm, ll, logit0, 1.0f);
    float lse = mm + __logf(ll);
    float contrib = logit0 - lse;
    atomicAdd(out, -contrib * (1.0f / (19.0f * 256.0f)));
  }
}

// ---------------- host ----------------
extern "C" void kernel_launch(void* const* d_in, const int* in_sizes, int n_in,
                              void* d_out, int out_size, void* d_ws, size_t ws_size,
                              hipStream_t stream) {
  const float* mu    = (const float*)d_in[0];
  const float* sg    = (const float*)d_in[1];
  const float* label = (const float*)d_in[2];
  const float* mask  = (const float*)d_in[3];
  const float* prob  = (const float*)d_in[4];
  const float* mmu   = (const float*)d_in[5];
  const float* msg   = (const float*)d_in[6];

  char* ws = (char*)d_ws;
  size_t off = 0;
  auto take = [&](size_t bytes) { size_t r = off; off = (off + bytes + 255) & ~(size_t)255; return r; };
  size_t o_pair8 = take((size_t)P_ * 128 * 4);   // 32 MB
  size_t o_rnrm  = take((size_t)P_ * 8);
  size_t o_cls   = take((size_t)P_ * 4);
  size_t o_hrd   = take((size_t)P_ * 4);
  size_t o_bcv   = take(S_ * 256 * 4);
  size_t o_bch   = take(S_ * 256 * 4);
  size_t o_bov   = take(S_ * 256 * 4);
  size_t o_boh   = take(S_ * 256 * 4);
  size_t o_cntv  = take(S_ * 4);
  size_t o_cnth  = take(S_ * 4);
  size_t o_basev = take(S_ * 4);
  size_t o_baseh = take(S_ * 4);
  size_t o_posv  = take((size_t)P_ * 4);
  size_t o_posh  = take((size_t)P_ * 4);
  size_t o_part  = take((size_t)256 * 2 * S_ * C_ * 4);
  size_t o_pmu   = take(S_ * C_ * 4);
  size_t o_psig  = take(S_ * C_ * 4);
  size_t o_phat  = take(S_ * C_ * 4);
  size_t o_logp  = take(S_ * 18 * 4);
  size_t o_keys  = take(S_ * 8 * 4);
  size_t o_aidx  = take(S_ * Q_ * 4);
  size_t o_nidx  = take((size_t)S_ * NS_ * 4);
  size_t o_snidx = take((size_t)S_ * NS_ * 4);
  size_t o_boff  = take((size_t)NANCH * 9 * 4);
  size_t o_lpar  = take((size_t)NANCH * NBUCK * 8);
  size_t o_ghat  = take((size_t)S_ * GENV_ * C_ * 4);
  if (ws_size < off) return;

  uint32_t* pair8 = (uint32_t*)(ws + o_pair8);
  float2*   rnrm  = (float2*)(ws + o_rnrm);
  int*      cls   = (int*)(ws + o_cls);
  int*      hrd   = (int*)(ws + o_hrd);
  int*      bcv   = (int*)(ws + o_bcv);
  int*      bch   = (int*)(ws + o_bch);
  int*      bov   = (int*)(ws + o_bov);
  int*      boh   = (int*)(ws + o_boh);
  int*      cntv  = (int*)(ws + o_cntv);
  int*      cnth  = (int*)(ws + o_cnth);
  int*      basev = (int*)(ws + o_basev);
  int*      baseh = (int*)(ws + o_baseh);
  int*      posv  = (int*)(ws + o_posv);
  int*      posh  = (int*)(ws + o_posh);
  float*    part  = (float*)(ws + o_part);
  float*    pmu   = (float*)(ws + o_pmu);
  float*    psig  = (float*)(ws + o_psig);
  float*    phat  = (float*)(ws + o_phat);
  float*    logp  = (float*)(ws + o_logp);
  uint32_t* keys  = (uint32_t*)(ws + o_keys);
  int*      aidx  = (int*)(ws + o_aidx);
  int*      nidx  = (int*)(ws + o_nidx);
  int*      snidx = (int*)(ws + o_snidx);
  int*      boff  = (int*)(ws + o_boff);
  float2*   lpar  = (float2*)(ws + o_lpar);
  float*    ghat  = (float*)(ws + o_ghat);

  hipMemsetAsync(d_out, 0, (size_t)out_size * 4, stream);

  k_classify<<<256, 256, 0, stream>>>(label, mask, prob, mu, keys, cls, hrd, bcv, bch, rnrm);
  k_pack<<<dim3(P_ / 64, C_ / 64), 256, 0, stream>>>(mu, sg, rnrm, pair8);
  k_scan<<<1, 320, 0, stream>>>(bcv, bch, bov, boh, cntv, cnth, basev, baseh);
  k_fillsums<<<256, 256, 0, stream>>>(pair8, rnrm, cls, hrd, bov, boh, basev, baseh, posv, posh, part);
  k_proto<<<S_, 1024, 0, stream>>>(part, mmu, msg, pmu, psig, phat);
  k_simlogp<<<S_, 64, 0, stream>>>(phat, psig, logp);
  k_gensample<<<GENV_ * S_ + 512 * S_, 256, 0, stream>>>(keys, pmu, psig, logp, cntv, basev, posv, ghat, nidx);
  k_bucket<<<NANCH, 64, 0, stream>>>(keys, cnth, baseh, posh, nidx, snidx, boff, aidx);
  k_neg<<<NBUCK * (NANCH / 4), 64, 0, stream>>>(pair8, snidx, boff, aidx, lpar);
  k_fin<<<NANCH, 256, 0, stream>>>(pair8, phat, psig, ghat, aidx, lpar, (float*)d_out);
}

// Round 12
// 579.741 us; speedup vs baseline: 1.3402x; 1.0119x over previous
//
#include <hip/hip_runtime.h>
#include <hip/hip_fp16.h>
#include <hip/hip_fp8.h>
#include <cstdint>

#define B_   4
#define S_   19
#define HW_  16384
#define P_   65536
#define C_   256
#define Q_   256
#define NEG_ 512
#define NS_  131072
#define GENV_ 144
#define NANCH (S_ * 256)     // 4864
#define NPAIR (NANCH / 2)    // 2432
#define NBUCK 8

typedef float v2f __attribute__((ext_vector_type(2)));

#if __has_builtin(__builtin_amdgcn_cvt_pk_f32_fp8) && __has_builtin(__builtin_amdgcn_cvt_pk_fp8_f32)
#define HAVE_HW_FP8 1
#endif

template<int W> __device__ __forceinline__ v2f cvt8(uint32_t d) {
#ifdef HAVE_HW_FP8
  v2f r = __builtin_amdgcn_cvt_pk_f32_fp8((int)d, W);
  return r;
#else
  __hip_fp8_e4m3 h0, h1;
  h0.__x = (uint8_t)(d >> (W * 16));
  h1.__x = (uint8_t)(d >> (W * 16 + 8));
  v2f r; r.x = (float)h0; r.y = (float)h1; return r;
#endif
}
template<int W> __device__ __forceinline__ uint32_t pk8(float a, float b, uint32_t old) {
#ifdef HAVE_HW_FP8
  return (uint32_t)__builtin_amdgcn_cvt_pk_fp8_f32(a, b, (int)old, W);
#else
  __hip_fp8_e4m3 ha(a), hb(b);
  uint32_t v = (uint32_t)ha.__x | ((uint32_t)hb.__x << 8);
  return (old & (W ? 0x0000FFFFu : 0xFFFF0000u)) | (v << (W * 16));
#endif
}

// ---------------- threefry2x32 (JAX-exact) ----------------
__device__ __forceinline__ void tf2x32(uint32_t k0, uint32_t k1, uint32_t x0, uint32_t x1,
                                       uint32_t& o0, uint32_t& o1) {
  uint32_t k2 = k0 ^ k1 ^ 0x1BD11BDAu;
#define TFR(r) { x0 += x1; x1 = (x1 << r) | (x1 >> (32 - r)); x1 ^= x0; }
  x0 += k0; x1 += k1;
  TFR(13) TFR(15) TFR(26) TFR(6)  x0 += k1; x1 += k2 + 1u;
  TFR(17) TFR(29) TFR(16) TFR(24) x0 += k2; x1 += k0 + 2u;
  TFR(13) TFR(15) TFR(26) TFR(6)  x0 += k0; x1 += k1 + 3u;
  TFR(17) TFR(29) TFR(16) TFR(24) x0 += k1; x1 += k2 + 4u;
  TFR(13) TFR(15) TFR(26) TFR(6)  x0 += k2; x1 += k0 + 5u;
#undef TFR
  o0 = x0; o1 = x1;
}

__device__ __forceinline__ uint32_t rbits(uint32_t k0, uint32_t k1, uint32_t n) {
  uint32_t a, b; tf2x32(k0, k1, 0u, n, a, b); return a ^ b;
}

__device__ __forceinline__ float bits2f01(uint32_t b) {
  return __uint_as_float((b >> 9) | 0x3f800000u) - 1.0f;
}

__device__ __forceinline__ float fastrcp(float x) {
  float r; asm("v_rcp_f32 %0, %1" : "=v"(r) : "v"(x)); return r;
}

__device__ __forceinline__ float wred(float v) {
#pragma unroll
  for (int off = 32; off > 0; off >>= 1) v += __shfl_xor(v, off, 64);
  return v;
}
__device__ __forceinline__ void wred3(float& a, float& b, float& c) {
#pragma unroll
  for (int off = 32; off > 0; off >>= 1) {
    a += __shfl_xor(a, off, 64);
    b += __shfl_xor(b, off, 64);
    c += __shfl_xor(c, off, 64);
  }
}

__device__ __forceinline__ void lse_up(float lg, float& m, float& l) {
  if (lg > m) { l = l * __expf(m - lg) + 1.0f; m = lg; }
  else l += __expf(lg - m);
}
__device__ __forceinline__ void lse_merge(float& m, float& l, float mo, float lo) {
  float mn = fmaxf(m, mo);
  l = l * __expf(m - mn) + lo * __expf(mo - mn);
  m = mn;
}

// XLA ErfInv32 (Giles)
__device__ __forceinline__ float erfinv_f(float x) {
  float w = -__logf(fmaxf(fmaf(-x, x, 1.0f), 1e-37f));
  float p;
  if (w < 5.0f) {
    w -= 2.5f;
    p = 2.81022636e-08f;
    p = fmaf(p, w, 3.43273939e-07f);
    p = fmaf(p, w, -3.5233877e-06f);
    p = fmaf(p, w, -4.39150654e-06f);
    p = fmaf(p, w, 0.00021858087f);
    p = fmaf(p, w, -0.00125372503f);
    p = fmaf(p, w, -0.00417768164f);
    p = fmaf(p, w, 0.246640727f);
    p = fmaf(p, w, 1.50140941f);
  } else {
    w = sqrtf(w) - 3.0f;
    p = -0.000200214257f;
    p = fmaf(p, w, 0.000100950558f);
    p = fmaf(p, w, 0.00134934322f);
    p = fmaf(p, w, -0.00367342844f);
    p = fmaf(p, w, 0.00573950773f);
    p = fmaf(p, w, -0.0076224613f);
    p = fmaf(p, w, 0.00943887047f);
    p = fmaf(p, w, 1.00167406f);
    p = fmaf(p, w, 2.83297682f);
  }
  return p * x;
}

// ---------------- K1: keys (block 0) + out zero + class/hard + per-block counts + mu norm ----------------
__global__ __launch_bounds__(256) void k_classify(const float* __restrict__ label,
    const float* __restrict__ mask, const float* __restrict__ prob,
    const float* __restrict__ mu,
    uint32_t* __restrict__ keys, int* __restrict__ cls, int* __restrict__ hrd,
    int* __restrict__ bcv, int* __restrict__ bch, float2* __restrict__ rnrm,
    float* __restrict__ out, int out_size) {
  __shared__ int hv[S_], hh[S_];
  int t = threadIdx.x;
  if (t < S_) { hv[t] = 0; hh[t] = 0; }
  if (blockIdx.x == 0) {
    if (t < S_) {
      uint32_t f0, f1;
      tf2x32(0u, 1234u, 0u, (uint32_t)t, f0, f1);
#pragma unroll
      for (int k = 0; k < 4; ++k) {
        uint32_t a, b;
        tf2x32(f0, f1, 0u, (uint32_t)k, a, b);
        keys[t * 8 + k * 2] = a; keys[t * 8 + k * 2 + 1] = b;
      }
    }
    for (int e = t; e < out_size; e += 256) out[e] = 0.0f;
  }
  __syncthreads();
  int p = blockIdx.x * 256 + t;
  int b = p >> 14, rem = p & (HW_ - 1);
  int sp = -1;
#pragma unroll
  for (int s = 0; s < S_; ++s) {
    float l = label[((b * S_ + s) << 14) + rem];
    if (l > 0.5f) sp = s;
  }
  if (mask[(b << 14) + rem] <= 0.5f) sp = -1;
  int h = 0;
  if (sp >= 0) h = (prob[((b * S_ + sp) << 14) + rem] < 0.97f) ? 1 : 0;
  cls[p] = sp; hrd[p] = h;
  if (sp >= 0) { atomicAdd(&hv[sp], 1); if (h) atomicAdd(&hh[sp], 1); }
  __syncthreads();
  if (t < S_) { bcv[t * 256 + blockIdx.x] = hv[t]; bch[t * 256 + blockIdx.x] = hh[t]; }
  // ---- fused: per-pixel mu norm (exact f32) ----
  const float* basep = mu + (((size_t)(b * C_)) << 14) + rem;
  float s2 = 0.f;
#pragma unroll 8
  for (int c = 0; c < C_; ++c) {
    float v = basep[(size_t)c << 14];
    s2 = fmaf(v, v, s2);
  }
  float nrm = sqrtf(s2);
  rnrm[p] = make_float2(fastrcp(fmaxf(nrm, 1e-12f)), nrm);
}

// ---------------- K1b: pack (B,C,H,W) f32 -> (P,C) fp8 {muhat, sg} interleaved ----------------
__global__ __launch_bounds__(256) void k_pack(const float* __restrict__ mu,
    const float* __restrict__ sg, const float2* __restrict__ rnrm,
    uint32_t* __restrict__ pair8) {
  __shared__ float smu[64][65];
  __shared__ float ssg[64][65];
  __shared__ float srn[64];
  int p0 = blockIdx.x * 64, c0 = blockIdx.y * 64;
  int b = p0 >> 14, rem0 = p0 & (HW_ - 1);
  if (threadIdx.x < 64) srn[threadIdx.x] = rnrm[p0 + threadIdx.x].x;
  int px = threadIdx.x & 63, cy = threadIdx.x >> 6;
#pragma unroll
  for (int itr = 0; itr < 16; ++itr) {
    int cl = cy + itr * 4;
    int addr = ((b * C_ + c0 + cl) << 14) + rem0 + px;
    smu[cl][px] = mu[addr];
    ssg[cl][px] = sg[addr];
  }
  __syncthreads();
#pragma unroll
  for (int itr = 0; itr < 8; ++itr) {
    int e = itr * 256 + threadIdx.x;
    int pxl = e >> 5, dw = e & 31, cl = dw * 2;
    float rn = srn[pxl];
    uint32_t wd = pk8<0>(smu[cl][pxl] * rn, ssg[cl][pxl], 0u);
    wd = pk8<1>(smu[cl + 1][pxl] * rn, ssg[cl + 1][pxl], wd);
    pair8[(size_t)(p0 + pxl) * 128 + (c0 >> 1) + dw] = wd;
  }
}

// parallel two-level scan: 304 workers of 16-entry chunks
__global__ __launch_bounds__(320) void k_scan(const int* __restrict__ bcv, const int* __restrict__ bch,
    int* __restrict__ bov, int* __restrict__ boh,
    int* __restrict__ cntv, int* __restrict__ cnth,
    int* __restrict__ basev, int* __restrict__ baseh) {
  __shared__ int psv[S_][16], psh[S_][16], scv[S_], sch[S_];
  int t = threadIdx.x;
  int s = t >> 4, c = t & 15;
  if (t < 304) {
    int sv = 0, sh = 0;
#pragma unroll 4
    for (int b = 0; b < 16; ++b) {
      sv += bcv[s * 256 + c * 16 + b];
      sh += bch[s * 256 + c * 16 + b];
    }
    psv[s][c] = sv; psh[s][c] = sh;
  }
  __syncthreads();
  if (t < S_) {
    int rv = 0, rh = 0;
#pragma unroll
    for (int cc = 0; cc < 16; ++cc) {
      int tv = psv[t][cc]; psv[t][cc] = rv; rv += tv;
      int th = psh[t][cc]; psh[t][cc] = rh; rh += th;
    }
    cntv[t] = rv; cnth[t] = rh; scv[t] = rv; sch[t] = rh;
  }
  __syncthreads();
  if (t == 0) {
    int bv = 0, bh = 0;
    for (int k = 0; k < S_; ++k) { basev[k] = bv; bv += scv[k]; baseh[k] = bh; bh += sch[k]; }
  }
  if (t < 304) {
    int rv = psv[s][c], rh = psh[s][c];
#pragma unroll 4
    for (int b = 0; b < 16; ++b) {
      int i0 = s * 256 + c * 16 + b;
      int tv = bcv[i0]; bov[i0] = rv; rv += tv;
      int th = bch[i0]; boh[i0] = rh; rh += th;
    }
  }
}

// ---------------- K2: fused fill (ballot-ranked pos lists) + per-class partial sums ----------------
__global__ __launch_bounds__(256) void k_fillsums(const uint32_t* __restrict__ pair8,
    const float2* __restrict__ rnrm, const int* __restrict__ cls, const int* __restrict__ hrd,
    const int* __restrict__ bov, const int* __restrict__ boh,
    const int* __restrict__ basev, const int* __restrict__ baseh,
    int* __restrict__ posv, int* __restrict__ posh, float* __restrict__ part) {
  __shared__ float lacc[S_][2][C_];   // 38 KB
  __shared__ int scls[256];
  __shared__ float snrm[256];
  __shared__ int cntW[4][S_], cnthW[4][S_];
  int t = threadIdx.x;
  int w = t >> 6, lane = t & 63;
  int p0 = blockIdx.x * 256;
  int p = p0 + t;
  int s = cls[p]; int h = hrd[p];
  scls[t] = s;
  snrm[t] = rnrm[p].y;
  for (int e = t; e < S_ * 2 * C_; e += 256) (&lacc[0][0][0])[e] = 0.f;
  // ---- ballot-based stable rank ----
  unsigned long long ltm = (1ull << lane) - 1ull;
  unsigned long long mv = 0ull, mh = 0ull;
  for (int sc = 0; sc < S_; ++sc) {
    unsigned long long mb = __ballot(s == sc);
    unsigned long long mbh = __ballot(s == sc && h);
    if (s == sc) { mv = mb; mh = mbh; }
    if (lane == 0) { cntW[w][sc] = (int)__popcll(mb); cnthW[w][sc] = (int)__popcll(mbh); }
  }
  __syncthreads();
  if (s >= 0) {
    int rv = (int)__popcll(mv & ltm);
    int rh = (int)__popcll(mh & ltm);
    for (int w2 = 0; w2 < w; ++w2) { rv += cntW[w2][s]; rh += cnthW[w2][s]; }
    posv[basev[s] + bov[s * 256 + blockIdx.x] + rv] = p;
    if (h) posh[baseh[s] + boh[s * 256 + blockIdx.x] + rh] = p;
  }
  // ---- sums: thread owns channel t ----
  int half = t & 1, dwi = t >> 1;
  uint32_t d = pair8[(size_t)p0 * 128 + dwi];
  for (int pp = 0; pp < 256; ++pp) {
    uint32_t dnx = (pp + 1 < 256) ? pair8[(size_t)(p0 + pp + 1) * 128 + dwi] : 0u;
    int sc = scls[pp];
    if (sc >= 0) {
      v2f e = half ? cvt8<1>(d) : cvt8<0>(d);
      float ia = fastrcp(e.y);
      lacc[sc][0][t] += ia;
      lacc[sc][1][t] += ia * e.x * snrm[pp];
    }
    d = dnx;
  }
  __syncthreads();
  float* dst = part + (size_t)blockIdx.x * (2 * S_ * C_);
  for (int e = t; e < S_ * 2 * C_; e += 256) dst[e] = (&lacc[0][0][0])[e];
}

// ---------------- K4: prototypes — 1024 threads, 4-way reduction over part blocks ----------------
__global__ __launch_bounds__(1024) void k_proto(const float* __restrict__ part,
    const float* __restrict__ mmu, const float* __restrict__ msg,
    float* __restrict__ pmu, float* __restrict__ psig, float* __restrict__ phat) {
  __shared__ float redA[4][C_];
  __shared__ float redB[4][C_];
  __shared__ float red[4];
  int s = blockIdx.x;
  int t = threadIdx.x;
  int c = t & 255, grp = t >> 8;
  float A = 0.f, Bv = 0.f;
  for (int b = grp * 64; b < grp * 64 + 64; ++b) {
    const float* pb = part + (size_t)b * (2 * S_ * C_) + (s * 2) * C_;
    A += pb[c];
    Bv += pb[C_ + c];
  }
  redA[grp][c] = A; redB[grp][c] = Bv;
  __syncthreads();
  float pm = 0.f;
  if (grp == 0) {
    A = redA[0][c] + redA[1][c] + redA[2][c] + redA[3][c];
    Bv = redB[0][c] + redB[1][c] + redB[2][c] + redB[3][c];
    int e = s * C_ + c;
    float psb = 1.0f / A;
    float pmb = psb * Bv;
    float ms = msg[e], mm = mmu[e];
    float ps = 1.0f / (1.0f / psb + 1.0f / ms);
    pm = ps * (mm / ms + pmb / psb);
    pmu[e] = pm; psig[e] = ps;
    float w = wred(pm * pm);
    int lane = c & 63, wv = c >> 6;
    if (lane == 0) red[wv] = w;
  }
  __syncthreads();
  if (grp == 0) {
    float tot = red[0] + red[1] + red[2] + red[3];
    float nrm = fmaxf(sqrtf(tot), 1e-12f);
    phat[s * C_ + c] = pm / nrm;
  }
}

// ---------------- K5a: sim -> log_softmax ----------------
__global__ __launch_bounds__(64) void k_simlogp(const float* __restrict__ phat,
    const float* __restrict__ psig, float* __restrict__ logp) {
  int i = blockIdx.x, lane = threadIdx.x;
  int c0 = lane * 4;
  float phi[4], psi[4];
#pragma unroll
  for (int k = 0; k < 4; ++k) { phi[k] = phat[i * C_ + c0 + k]; psi[k] = psig[i * C_ + c0 + k]; }
  float xs[18];
#pragma unroll
  for (int j = 0; j < 18; ++j) {
    int o = i + 1 + j; if (o >= S_) o -= S_;
    float t = 0.f;
#pragma unroll
    for (int k = 0; k < 4; ++k) {
      float d = phi[k] - phat[o * C_ + c0 + k];
      float dn = psi[k] + psig[o * C_ + c0 + k];
      t += d * d / dn + logf(dn);
    }
    t = wred(t);
    xs[j] = (-0.5f * t * (1.0f / 256.0f)) * 2.0f;
  }
  float m = xs[0];
#pragma unroll
  for (int j = 1; j < 18; ++j) m = fmaxf(m, xs[j]);
  float se = 0.f;
#pragma unroll
  for (int j = 0; j < 18; ++j) se += expf(xs[j] - m);
  float lg = logf(se);
  if (lane == 0) {
#pragma unroll
    for (int j = 0; j < 18; ++j) logp[i * 18 + j] = xs[j] - m - lg;
  }
}

// ---------------- K5bc: fused generalized prototypes + class/negative sampling ----------------
__global__ __launch_bounds__(256) void k_gensample(const uint32_t* __restrict__ keys,
    const float* __restrict__ pmu, const float* __restrict__ psig,
    const float* __restrict__ logp, const int* __restrict__ cntv, const int* __restrict__ basev,
    const int* __restrict__ posv, float* __restrict__ ghat, int* __restrict__ nidx) {
  __shared__ float red[4];
  __shared__ float elp[18];
  __shared__ int lcnt[S_], lbase[S_];
  int bid = blockIdx.x;
  int t = threadIdx.x;
  if (bid < GENV_ * S_) {
    // ---- gen ----
    int v = bid % GENV_, i = bid / GENV_;
    int c = t;
    int o = i + 1 + (v >> 3); if (o >= S_) o -= S_;
    uint32_t k0 = keys[i * 8 + 6], k1 = keys[i * 8 + 7];
    uint32_t bits = rbits(k0, k1, (uint32_t)(v * C_ + c));
    float f01 = bits2f01(bits);
    const float lo = -0.99999994f;
    float u = fmaxf(f01 * 2.0f + lo, lo);
    float eps = 1.41421356237f * erfinv_f(u);
    float g = pmu[o * C_ + c] + sqrtf(psig[o * C_ + c]) * eps;
    float w = wred(g * g);
    int lane = c & 63, wv = c >> 6;
    if (lane == 0) red[wv] = w;
    __syncthreads();
    float tot = red[0] + red[1] + red[2] + red[3];
    float nrm = fmaxf(sqrtf(tot), 1e-12f);
    ghat[((size_t)(i * GENV_ + v)) * C_ + c] = g / nrm;
  } else {
    // ---- sample ----
    int sid = bid - GENV_ * S_;
    int i = sid / 512;
    int m = (sid % 512) * 256 + t;
    if (t < 18) elp[t] = __expf(-logp[i * 18 + t]);
    if (t < S_) { lcnt[t] = cntv[t]; lbase[t] = basev[t]; }
    __syncthreads();
    uint32_t kc0 = keys[i * 8 + 2], kc1 = keys[i * 8 + 3];
    uint32_t kn0 = keys[i * 8 + 4], kn1 = keys[i * 8 + 5];
    // argmax_s( -log(-log u_s) + lp_s ) == argmin_s( (-log u_s) * exp(-lp_s) )
    float bv = 1e30f; int best = 0;
    for (int s = 0; s < 18; ++s) {
      uint32_t b = rbits(kc0, kc1, (uint32_t)m * 18u + (uint32_t)s);
      float u = fmaxf(bits2f01(b), 1.17549435e-38f);
      float val = (-__logf(u)) * elp[s];
      if (val < bv) { bv = val; best = s; }
    }
    float un = bits2f01(rbits(kn0, kn1, (uint32_t)m));
    int cc = i + 1 + best; if (cc >= S_) cc -= S_;
    int cnt = lcnt[cc];
    int idx = P_ - 1;
    if (cnt > 0) {
      int kk = (int)(un * (float)cnt);
      if (kk >= cnt) kk = cnt - 1;
      idx = posv[lbase[cc] + kk];
    }
    nidx[(size_t)i * NS_ + m] = idx;
  }
}

// ---------------- K5e: bucket sort of negatives + anchor index (fused) ----------------
__global__ __launch_bounds__(64) void k_bucket(const uint32_t* __restrict__ keys,
    const int* __restrict__ cnth, const int* __restrict__ baseh, const int* __restrict__ posh,
    const int* __restrict__ nidx, int* __restrict__ snidx, int* __restrict__ boff,
    int* __restrict__ aidx) {
  int a = blockIdx.x;
  int lane = threadIdx.x;
  if (lane == 0) {
    int i = a >> 8, q = a & 255;
    uint32_t k0 = keys[i * 8 + 0], k1 = keys[i * 8 + 1];
    float u = bits2f01(rbits(k0, k1, (uint32_t)q));
    int cnt = cnth[i];
    int idx = P_ - 1;
    if (cnt > 0) {
      int kk = (int)(u * (float)cnt);
      if (kk >= cnt) kk = cnt - 1;
      idx = posh[baseh[i] + kk];
    }
    aidx[a] = idx;
  }
  const int* src = nidx + (size_t)a * NEG_;
  int e[8], bk[8];
#pragma unroll
  for (int c = 0; c < 8; ++c) { e[c] = src[c * 64 + lane]; bk[c] = (e[c] >> 13) & 7; }
  uint32_t cnt[NBUCK];
#pragma unroll
  for (int b = 0; b < NBUCK; ++b) cnt[b] = 0;
#pragma unroll
  for (int c = 0; c < 8; ++c)
#pragma unroll
    for (int b = 0; b < NBUCK; ++b) {
      unsigned long long mb = __ballot(bk[c] == b);
      cnt[b] += (uint32_t)__popcll(mb);
    }
  uint32_t base[NBUCK]; uint32_t run = 0;
#pragma unroll
  for (int b = 0; b < NBUCK; ++b) { base[b] = run; run += cnt[b]; }
  if (lane < NBUCK) boff[a * 9 + lane] = (int)base[lane];
  if (lane == 0) boff[a * 9 + 8] = NEG_;
  uint32_t off[NBUCK];
#pragma unroll
  for (int b = 0; b < NBUCK; ++b) off[b] = 0;
  unsigned long long ltm = (1ull << lane) - 1ull;
#pragma unroll
  for (int c = 0; c < 8; ++c) {
    int pos = 0;
#pragma unroll
    for (int b = 0; b < NBUCK; ++b) {
      unsigned long long mb = __ballot(bk[c] == b);
      if (bk[c] == b) pos = (int)(base[b] + off[b] + (uint32_t)__popcll(mb & ltm));
      off[b] += (uint32_t)__popcll(mb);
    }
    snidx[(size_t)a * NEG_ + pos] = e[c];
  }
}

// ---------------- K6a: negatives — R10 proven shape (2 anchors, 64 threads) ----------------
__global__ __launch_bounds__(64) void k_neg(const uint32_t* __restrict__ pair8,
    const int* __restrict__ snidx, const int* __restrict__ boff,
    const int* __restrict__ aidx, float2* __restrict__ partial) {
  __shared__ float4 anc[260];    // two regions: [0..128), [130..258) — bank-staggered
  int bid = blockIdx.x;
  int bucket = bid & 7;          // XCD-affine
  int pr = bid >> 3;
  int a0 = pr * 2, a1 = a0 + 1;
  int lane = threadIdx.x;

  int ap0 = aidx[a0], ap1 = aidx[a1];
  uint2 d0 = ((const uint2*)(pair8 + (size_t)ap0 * 128))[lane];
  uint2 d1 = ((const uint2*)(pair8 + (size_t)ap1 * 128))[lane];
  {
    v2f ex = cvt8<0>(d0.x), ey = cvt8<1>(d0.x), ez = cvt8<0>(d0.y), ew = cvt8<1>(d0.y);
    anc[lane * 2]     = make_float4(ex.x, ex.y, ey.x, ey.y);
    anc[lane * 2 + 1] = make_float4(ez.x, ez.y, ew.x, ew.y);
    ex = cvt8<0>(d1.x); ey = cvt8<1>(d1.x); ez = cvt8<0>(d1.y); ew = cvt8<1>(d1.y);
    anc[130 + lane * 2]     = make_float4(ex.x, ex.y, ey.x, ey.y);
    anc[130 + lane * 2 + 1] = make_float4(ez.x, ez.y, ew.x, ew.y);
  }
  __syncthreads();

  int s0 = boff[a0 * 9 + bucket], e0i = boff[a0 * 9 + bucket + 1];
  int s1 = boff[a1 * 9 + bucket], e1i = boff[a1 * 9 + bucket + 1];
  int L0 = e0i - s0, L1 = e1i - s1, Lt = L0 + L1;
  const int* list0 = snidx + (size_t)a0 * NEG_ + s0;
  const int* list1 = snidx + (size_t)a1 * NEG_ + s1;

  float m0 = -1e30f, l0 = 0.f, m1 = -1e30f, l1 = 0.f;

  for (int r = 0; r * 64 < Lt; ++r) {
    int g = r * 64 + lane;
    bool act = g < Lt;
    int which = (act && g >= L0) ? 1 : 0;
    int j = which ? (g - L0) : g;
    int p = act ? (which ? list1[j] : list0[j]) : ap0;
    const uint4* rp = (const uint4*)(pair8 + (size_t)p * 128);
    const float4* A = anc + which * 130;
    float sT = 0.f, sL = 0.f;
    uint4 c0 = rp[0], c1 = rp[1];
#pragma unroll 1
    for (int it = 0; it < 16; ++it) {
      int nx = ((it + 1) & 15) * 2;
      uint4 n0 = rp[nx], n1 = rp[nx + 1];
      uint32_t dws[8] = {c0.x, c0.y, c0.z, c0.w, c1.x, c1.y, c1.z, c1.w};
      float pp = 1.0f, pq = 1.0f;
#pragma unroll
      for (int gq = 0; gq < 4; ++gq) {
        float4 acA = A[it * 8 + gq * 2];
        float4 acB = A[it * 8 + gq * 2 + 1];
        v2f e0v = cvt8<0>(dws[2 * gq]),     e1v = cvt8<1>(dws[2 * gq]);
        v2f e2v = cvt8<0>(dws[2 * gq + 1]), e3v = cvt8<1>(dws[2 * gq + 1]);
        float dn0 = acA.y + e0v.y, dn1 = acA.w + e1v.y;
        float dn2 = acB.y + e2v.y, dn3 = acB.w + e3v.y;
        float d01 = dn0 * dn1, d23 = dn2 * dn3;
        float R01 = fastrcp(d01), R23 = fastrcp(d23);
        pp *= d01; pq *= d23;
        float r0 = dn1 * R01, r1 = dn0 * R01, r2 = dn3 * R23, r3 = dn2 * R23;
        float f0 = acA.x - e0v.x, f1 = acA.z - e1v.x;
        float f2 = acB.x - e2v.x, f3 = acB.z - e3v.x;
        sT = fmaf(f0 * f0, r0, sT); sT = fmaf(f1 * f1, r1, sT);
        sT = fmaf(f2 * f2, r2, sT); sT = fmaf(f3 * f3, r3, sT);
      }
      sL += __logf(pp * pq);   // 16-ch product, range [0.2^16, 2^16] — safe
      c0 = n0; c1 = n1;
    }
    float lg = -(sT + sL) * (1.0f / 256.0f);
    if (act) { if (which) lse_up(lg, m1, l1); else lse_up(lg, m0, l0); }
  }
#pragma unroll
  for (int o = 32; o > 0; o >>= 1) {
    float mo = __shfl_xor(m0, o, 64), lo = __shfl_xor(l0, o, 64);
    lse_merge(m0, l0, mo, lo);
    mo = __shfl_xor(m1, o, 64); lo = __shfl_xor(l1, o, 64);
    lse_merge(m1, l1, mo, lo);
  }
  if (lane == 0) {
    partial[a0 * NBUCK + bucket] = make_float2(m0, l0);
    partial[a1 * NBUCK + bucket] = make_float2(m1, l1);
  }
}

// ---------------- K6b: pos + gens + merge partials ----------------
__global__ __launch_bounds__(256, 4) void k_fin(const uint32_t* __restrict__ pair8,
    const float* __restrict__ phat, const float* __restrict__ psig,
    const float* __restrict__ ghat, const int* __restrict__ aidx,
    const float2* __restrict__ partial, float* __restrict__ out) {
  __shared__ float2 ancG[C_];   // {w, ahat*w}
  __shared__ float redm[3][4];
  __shared__ float2 mlw[4];

  int bid = blockIdx.x;
  int i = bid >> 8;
  int t = threadIdx.x, w = t >> 6, lane = t & 63;

  int ap = aidx[bid];
  uint32_t ad = pair8[(size_t)ap * 128 + (t >> 1)];
  v2f ae0 = cvt8<0>(ad), ae1 = cvt8<1>(ad);
  float ahat = (t & 1) ? ae1.x : ae0.x;
  float asg = (t & 1) ? ae1.y : ae0.y;
  float wv = fastrcp(asg);
  ancG[t] = make_float2(wv, ahat * wv);

  float pm = phat[i * C_ + t];
  float ps = psig[i * C_ + t];
  float dnp = asg + ps;
  float dd = ahat - pm;
  float post = fmaf(dd * dd, fastrcp(dnp), __logf(dnp));
  float a1t = ahat * ahat * wv;
  float lat = __logf(asg);
  wred3(post, a1t, lat);
  if (lane == 0) { redm[0][w] = post; redm[1][w] = a1t; redm[2][w] = lat; }
  __syncthreads();
  float postS = redm[0][0] + redm[0][1] + redm[0][2] + redm[0][3];
  float Kc = (redm[1][0] + redm[1][1] + redm[1][2] + redm[1][3])
           + (redm[2][0] + redm[2][1] + redm[2][2] + redm[2][3]);
  float logit0 = -postS * (1.0f / 256.0f);

  float m = -1e30f, l = 0.0f;
  const float4* ancGf = (const float4*)ancG;
  if (lane < 36) {
    int g = lane * 4 + w;
    const float4* gp = (const float4*)(ghat + ((size_t)(i * GENV_ + g)) * C_);
    float a1 = 0.f, a2 = 0.f;
    for (int itr = 0; itr < 64; ++itr) {
      float4 gv = gp[itr];
      float4 g01 = ancGf[itr * 2];
      float4 g23 = ancGf[itr * 2 + 1];
      a1 = fmaf(gv.x * gv.x, g01.x, a1); a2 = fmaf(gv.x, g01.y, a2);
      a1 = fmaf(gv.y * gv.y, g01.z, a1); a2 = fmaf(gv.y, g01.w, a2);
      a1 = fmaf(gv.z * gv.z, g23.x, a1); a2 = fmaf(gv.z, g23.y, a2);
      a1 = fmaf(gv.w * gv.w, g23.z, a1); a2 = fmaf(gv.w, g23.w, a2);
    }
    float lg = -(Kc + a1 - 2.0f * a2) * (1.0f / 256.0f);
    lse_up(lg, m, l);
  }
#pragma unroll
  for (int o = 32; o > 0; o >>= 1) {
    float mo = __shfl_xor(m, o, 64);
    float lo = __shfl_xor(l, o, 64);
    lse_merge(m, l, mo, lo);
  }
  if (lane == 0) mlw[w] = make_float2(m, l);
  __syncthreads();
  if (t == 0) {
    float mm = mlw[0].x, ll = mlw[0].y;
    lse_merge(mm, ll, mlw[1].x, mlw[1].y);
    lse_merge(mm, ll, mlw[2].x, mlw[2].y);
    lse_merge(mm, ll, mlw[3].x, mlw[3].y);
    const float2* pp = partial + (size_t)bid * NBUCK;
#pragma unroll
    for (int b = 0; b < NBUCK; ++b) lse_merge(mm, ll, pp[b].x, pp[b].y);
    lse_merge(mm, ll, logit0, 1.0f);
    float lse = mm + __logf(ll);
    float contrib = logit0 - lse;
    atomicAdd(out, -contrib * (1.0f / (19.0f * 256.0f)));
  }
}

// ---------------- host ----------------
extern "C" void kernel_launch(void* const* d_in, const int* in_sizes, int n_in,
                              void* d_out, int out_size, void* d_ws, size_t ws_size,
                              hipStream_t stream) {
  const float* mu    = (const float*)d_in[0];
  const float* sg    = (const float*)d_in[1];
  const float* label = (const float*)d_in[2];
  const float* mask  = (const float*)d_in[3];
  const float* prob  = (const float*)d_in[4];
  const float* mmu   = (const float*)d_in[5];
  const float* msg   = (const float*)d_in[6];

  char* ws = (char*)d_ws;
  size_t off = 0;
  auto take = [&](size_t bytes) { size_t r = off; off = (off + bytes + 255) & ~(size_t)255; return r; };
  size_t o_pair8 = take((size_t)P_ * 128 * 4);   // 32 MB
  size_t o_rnrm  = take((size_t)P_ * 8);
  size_t o_cls   = take((size_t)P_ * 4);
  size_t o_hrd   = take((size_t)P_ * 4);
  size_t o_bcv   = take(S_ * 256 * 4);
  size_t o_bch   = take(S_ * 256 * 4);
  size_t o_bov   = take(S_ * 256 * 4);
  size_t o_boh   = take(S_ * 256 * 4);
  size_t o_cntv  = take(S_ * 4);
  size_t o_cnth  = take(S_ * 4);
  size_t o_basev = take(S_ * 4);
  size_t o_baseh = take(S_ * 4);
  size_t o_posv  = take((size_t)P_ * 4);
  size_t o_posh  = take((size_t)P_ * 4);
  size_t o_part  = take((size_t)256 * 2 * S_ * C_ * 4);
  size_t o_pmu   = take(S_ * C_ * 4);
  size_t o_psig  = take(S_ * C_ * 4);
  size_t o_phat  = take(S_ * C_ * 4);
  size_t o_logp  = take(S_ * 18 * 4);
  size_t o_keys  = take(S_ * 8 * 4);
  size_t o_aidx  = take(S_ * Q_ * 4);
  size_t o_nidx  = take((size_t)S_ * NS_ * 4);
  size_t o_snidx = take((size_t)S_ * NS_ * 4);
  size_t o_boff  = take((size_t)NANCH * 9 * 4);
  size_t o_lpar  = take((size_t)NANCH * NBUCK * 8);
  size_t o_ghat  = take((size_t)S_ * GENV_ * C_ * 4);
  if (ws_size < off) return;

  uint32_t* pair8 = (uint32_t*)(ws + o_pair8);
  float2*   rnrm  = (float2*)(ws + o_rnrm);
  int*      cls   = (int*)(ws + o_cls);
  int*      hrd   = (int*)(ws + o_hrd);
  int*      bcv   = (int*)(ws + o_bcv);
  int*      bch   = (int*)(ws + o_bch);
  int*      bov   = (int*)(ws + o_bov);
  int*      boh   = (int*)(ws + o_boh);
  int*      cntv  = (int*)(ws + o_cntv);
  int*      cnth  = (int*)(ws + o_cnth);
  int*      basev = (int*)(ws + o_basev);
  int*      baseh = (int*)(ws + o_baseh);
  int*      posv  = (int*)(ws + o_posv);
  int*      posh  = (int*)(ws + o_posh);
  float*    part  = (float*)(ws + o_part);
  float*    pmu   = (float*)(ws + o_pmu);
  float*    psig  = (float*)(ws + o_psig);
  float*    phat  = (float*)(ws + o_phat);
  float*    logp  = (float*)(ws + o_logp);
  uint32_t* keys  = (uint32_t*)(ws + o_keys);
  int*      aidx  = (int*)(ws + o_aidx);
  int*      nidx  = (int*)(ws + o_nidx);
  int*      snidx = (int*)(ws + o_snidx);
  int*      boff  = (int*)(ws + o_boff);
  float2*   lpar  = (float2*)(ws + o_lpar);
  float*    ghat  = (float*)(ws + o_ghat);

  k_classify<<<256, 256, 0, stream>>>(label, mask, prob, mu, keys, cls, hrd, bcv, bch, rnrm,
                                      (float*)d_out, out_size);
  k_pack<<<dim3(P_ / 64, C_ / 64), 256, 0, stream>>>(mu, sg, rnrm, pair8);
  k_scan<<<1, 320, 0, stream>>>(bcv, bch, bov, boh, cntv, cnth, basev, baseh);
  k_fillsums<<<256, 256, 0, stream>>>(pair8, rnrm, cls, hrd, bov, boh, basev, baseh, posv, posh, part);
  k_proto<<<S_, 1024, 0, stream>>>(part, mmu, msg, pmu, psig, phat);
  k_simlogp<<<S_, 64, 0, stream>>>(phat, psig, logp);
  k_gensample<<<GENV_ * S_ + 512 * S_, 256, 0, stream>>>(keys, pmu, psig, logp, cntv, basev, posv, ghat, nidx);
  k_bucket<<<NANCH, 64, 0, stream>>>(keys, cnth, baseh, posh, nidx, snidx, boff, aidx);
  k_neg<<<NBUCK * NPAIR, 64, 0, stream>>>(pair8, snidx, boff, aidx, lpar);
  k_fin<<<NANCH, 256, 0, stream>>>(pair8, phat, psig, ghat, aidx, lpar, (float*)d_out);
}